// Round 4
// baseline (275.067 us; speedup 1.0000x reference)
//
#include <hip/hip_runtime.h>
#include <math.h>

typedef unsigned short u16;
typedef __attribute__((ext_vector_type(8))) short bffrag;   // 8 bf16 MFMA operand
typedef __attribute__((ext_vector_type(4))) float f32x4;    // MFMA accumulator
typedef __attribute__((ext_vector_type(4))) unsigned short us4;
typedef __attribute__((ext_vector_type(8))) unsigned short us8;

#define SCALE_QK (1.0f/32.0f)

// fp32 -> bf16 round-to-nearest-even (bit trick, NaN-free inputs)
__device__ __forceinline__ u16 f2bf(float f) {
    unsigned u = __builtin_bit_cast(unsigned, f);
    u += 0x7fffu + ((u >> 16) & 1u);
    return (u16)(u >> 16);
}

__device__ __forceinline__ void gld16(const u16* g, u16* l) {
    __builtin_amdgcn_global_load_lds(
        (const __attribute__((address_space(1))) void*)g,
        (__attribute__((address_space(3))) void*)l, 16, 0, 0);
}

// ---------------- router (fp32, exact) ----------------
__global__ __launch_bounds__(256) void router_partial(const float* __restrict__ X,
                                                      const float* __restrict__ sW,
                                                      float* __restrict__ part) {
    float acc[32];
    #pragma unroll
    for (int a = 0; a < 32; ++a) acc[a] = 0.f;
    int tid = blockIdx.x * 256 + threadIdx.x;
    #pragma unroll
    for (int q = 0; q < 4; ++q) {
        int i = tid + q * 262144;
        float4 w0 = *(const float4*)(sW + (size_t)i * 8);
        float4 w1 = *(const float4*)(sW + (size_t)i * 8 + 4);
        #pragma unroll
        for (int b = 0; b < 4; ++b) {
            float x = X[((size_t)b << 20) + i];
            acc[b*8+0] += x * w0.x; acc[b*8+1] += x * w0.y;
            acc[b*8+2] += x * w0.z; acc[b*8+3] += x * w0.w;
            acc[b*8+4] += x * w1.x; acc[b*8+5] += x * w1.y;
            acc[b*8+6] += x * w1.z; acc[b*8+7] += x * w1.w;
        }
    }
    __shared__ float wsum[4][32];
    int lane = threadIdx.x & 63, wv = threadIdx.x >> 6;
    #pragma unroll
    for (int a = 0; a < 32; ++a) {
        float v = acc[a];
        #pragma unroll
        for (int off = 32; off; off >>= 1) v += __shfl_down(v, off, 64);
        if (lane == 0) wsum[wv][a] = v;
    }
    __syncthreads();
    int t = threadIdx.x;
    if (t < 32)
        part[(size_t)t * 1024 + blockIdx.x] = wsum[0][t] + wsum[1][t] + wsum[2][t] + wsum[3][t];
}

// reduce partials, add bias, top-2 per batch (ties -> lowest index), publish need flags
__global__ __launch_bounds__(256) void router_final(const float* __restrict__ part,
                                                    const float* __restrict__ sb,
                                                    int* __restrict__ sel_need) {
    __shared__ float ps[32][8];
    __shared__ float lg[32];
    int t = threadIdx.x, a = t >> 3, c = t & 7;
    {
        float s = 0.f;
        const float* p = part + (size_t)a * 1024 + c * 128;
        for (int i = 0; i < 128; ++i) s += p[i];
        ps[a][c] = s;
    }
    __syncthreads();
    if (t < 32) {
        float v = 0.f;
        #pragma unroll
        for (int j = 0; j < 8; ++j) v += ps[t][j];
        lg[t] = v + sb[t & 7];
    }
    __syncthreads();
    if (t < 4) {
        int base = t * 8;
        int e1 = 0; float v1 = lg[base];
        for (int e = 1; e < 8; ++e) { if (lg[base + e] > v1) { v1 = lg[base + e]; e1 = e; } }
        int e2 = -1; float v2 = -INFINITY;
        for (int e = 0; e < 8; ++e) {
            if (e == e1) continue;
            if (lg[base + e] > v2) { v2 = lg[base + e]; e2 = e; }
        }
        sel_need[t * 2] = e1; sel_need[t * 2 + 1] = e2;
    }
    __syncthreads();
    if (t < 8) {
        int need = 0;
        for (int j = 0; j < 8; ++j) need |= (sel_need[j] == t);
        sel_need[8 + t] = need;
    }
}

// ---------------- converts ----------------
__global__ __launch_bounds__(256) void cvt_x(const float* __restrict__ X, u16* __restrict__ Xb) {
    size_t i = (size_t)(blockIdx.x * 256 + threadIdx.x) * 8;
    float4 a = *(const float4*)(X + i);
    float4 b = *(const float4*)(X + i + 4);
    us8 o;
    o[0] = f2bf(a.x); o[1] = f2bf(a.y); o[2] = f2bf(a.z); o[3] = f2bf(a.w);
    o[4] = f2bf(b.x); o[5] = f2bf(b.y); o[6] = f2bf(b.z); o[7] = f2bf(b.w);
    *(us8*)(Xb + i) = o;
}

// plain convert per-expert matrix (need-gated): Wv row-major -> bf16
__global__ __launch_bounds__(256) void cvt_plain(const float* __restrict__ src,
                                                 const int* __restrict__ sel_need,
                                                 u16* __restrict__ dst) {
    int e = blockIdx.y;
    if (!sel_need[8 + e]) return;
    size_t i = ((size_t)e << 20) + (size_t)(blockIdx.x * 256 + threadIdx.x) * 8;
    float4 a = *(const float4*)(src + i);
    float4 b = *(const float4*)(src + i + 4);
    us8 o;
    o[0] = f2bf(a.x); o[1] = f2bf(a.y); o[2] = f2bf(a.z); o[3] = f2bf(a.w);
    o[4] = f2bf(b.x); o[5] = f2bf(b.y); o[6] = f2bf(b.z); o[7] = f2bf(b.w);
    *(us8*)(dst + i) = o;
}

// transpose + convert selected experts' Wq/Wk/Wff -> bf16 transposed.
// 128x128 tile; LDS row stride 136 u16 (272B = 17*16B: phase-2 b128 reads aligned
// + conflict-free; phase-1 b64 writes ~2-way).
__global__ __launch_bounds__(256) void cvt_wt(const float* __restrict__ Wq,
                                              const float* __restrict__ Wk,
                                              const float* __restrict__ Wff,
                                              const int* __restrict__ sel_need,
                                              u16* __restrict__ WqT, u16* __restrict__ WkT,
                                              u16* __restrict__ WffT) {
    int z = blockIdx.z;                  // 0..23
    int type = z >> 3, e = z & 7;
    if (!sel_need[8 + e]) return;
    const float* src = (type == 0 ? Wq : type == 1 ? Wk : Wff) + ((size_t)e << 20);
    u16* dst = (type == 0 ? WqT : type == 1 ? WkT : WffT) + ((size_t)e << 20);
    __shared__ u16 lt[128 * 136];
    int R0 = blockIdx.y * 128, C0 = blockIdx.x * 128;
    int t = threadIdx.x;
    int c = t & 127;
    int rh = (t >> 7) * 4;               // 0 or 4
    #pragma unroll
    for (int it = 0; it < 16; ++it) {
        int r4 = it * 8 + rh;
        us4 o;
        #pragma unroll
        for (int j = 0; j < 4; ++j)
            o[j] = f2bf(src[(size_t)(R0 + r4 + j) * 1024 + C0 + c]);
        *(us4*)&lt[c * 136 + r4] = o;
    }
    __syncthreads();
    int dd = (t & 15) * 8;
    int hh = t >> 4;                     // 0..15
    #pragma unroll
    for (int it = 0; it < 8; ++it) {
        int cr = it * 16 + hh;           // dst row (src col)
        us8 o = *(const us8*)&lt[cr * 136 + dd];
        *(us8*)(dst + (size_t)(C0 + cr) * 1024 + R0 + dd) = o;
    }
}

// ---------------- MFMA GEMM core: C[m][n] = sum_k A[m][k]*B[n][k] ----------------
// 128x128 tile, BK=32, 4 waves (2x2), 16x16x32 bf16 MFMA, dbuf prefetch.
// Both A and B support a k-split (concat of two source matrices along k).
__device__ __forceinline__ void stage_tile(const u16* a0, const u16* a1,
                                           const u16* b0, const u16* b1,
                                           u16* sa, u16* sb, int tid) {
    gld16(a0, &sa[tid * 8]);
    gld16(a1, &sa[2048 + tid * 8]);
    gld16(b0, &sb[tid * 8]);
    gld16(b1, &sb[2048 + tid * 8]);
}

__device__ __forceinline__ void gemm_ds(const u16* __restrict__ A0, const u16* __restrict__ A1,
                                        int asplit, int lda,
                                        const u16* __restrict__ B0, const u16* __restrict__ B1,
                                        int bsplit, int ldb, int K, f32x4 (&acc)[4][4]) {
    __shared__ u16 sA[2][4096];
    __shared__ u16 sB[2][4096];
    const int tid = threadIdx.x, lane = tid & 63, wv = tid >> 6;
    const int wr = (wv >> 1) * 64, wc = (wv & 1) * 64;
    const int l15 = lane & 15, lk = (lane >> 4) * 8;
    const int m0 = blockIdx.y * 128, n0 = blockIdx.x * 128;
    const int r0 = tid >> 2, k8 = (tid & 3) * 8;

    // prologue: stage tile 0
    stage_tile(A0 + (size_t)(m0 + r0) * lda + k8,
               A0 + (size_t)(m0 + 64 + r0) * lda + k8,
               B0 + (size_t)(n0 + r0) * ldb + k8,
               B0 + (size_t)(n0 + 64 + r0) * ldb + k8,
               sA[0], sB[0], tid);
    __syncthreads();

    const int nt = K >> 5;
    for (int t = 0; t < nt; ++t) {
        const int cur = t & 1;
        if (t + 1 < nt) {
            int k0 = (t + 1) << 5;
            const u16* Ap; int ka;
            if (k0 < asplit) { Ap = A0; ka = k0; } else { Ap = A1; ka = k0 - asplit; }
            const u16* Bp; int kb;
            if (k0 < bsplit) { Bp = B0; kb = k0; } else { Bp = B1; kb = k0 - bsplit; }
            stage_tile(Ap + (size_t)(m0 + r0) * lda + ka + k8,
                       Ap + (size_t)(m0 + 64 + r0) * lda + ka + k8,
                       Bp + (size_t)(n0 + r0) * ldb + kb + k8,
                       Bp + (size_t)(n0 + 64 + r0) * ldb + kb + k8,
                       sA[cur ^ 1], sB[cur ^ 1], tid);
        }
        bffrag av[4], bf[4];
        #pragma unroll
        for (int m = 0; m < 4; ++m)
            av[m] = *reinterpret_cast<const bffrag*>(&sA[cur][(wr + m * 16 + l15) * 32 + lk]);
        #pragma unroll
        for (int n = 0; n < 4; ++n)
            bf[n] = *reinterpret_cast<const bffrag*>(&sB[cur][(wc + n * 16 + l15) * 32 + lk]);
        #pragma unroll
        for (int m = 0; m < 4; ++m)
            #pragma unroll
            for (int n = 0; n < 4; ++n)
                acc[m][n] = __builtin_amdgcn_mfma_f32_16x16x32_bf16(av[m], bf[n], acc[m][n], 0, 0, 0);
        __syncthreads();   // drains prefetch vmcnt + protects buf reuse
    }
}

__device__ __forceinline__ void zero_acc(f32x4 (&acc)[4][4]) {
    #pragma unroll
    for (int m = 0; m < 4; ++m)
        #pragma unroll
        for (int n = 0; n < 4; ++n)
            #pragma unroll
            for (int i = 0; i < 4; ++i) acc[m][n][i] = 0.f;
}

// D layout: col = lane&15 (+n*16), row = (lane>>4)*4 + i (+m*16)  [m89/m91 verified]
__device__ __forceinline__ void epilogue_bf16(u16* __restrict__ C, int ldc, int coloff,
                                              const f32x4 (&acc)[4][4],
                                              const float* __restrict__ biasN,
                                              const float* __restrict__ biasM) {
    const int tid = threadIdx.x, lane = tid & 63, wv = tid >> 6;
    const int wr = (wv >> 1) * 64, wc = (wv & 1) * 64;
    const int m0 = blockIdx.y * 128, n0 = blockIdx.x * 128;
    const int l15 = lane & 15, l4 = (lane >> 4) * 4;
    #pragma unroll
    for (int m = 0; m < 4; ++m) {
        #pragma unroll
        for (int n = 0; n < 4; ++n) {
            int col = n0 + wc + n * 16 + l15;
            float bn = biasN ? biasN[col] : 0.f;
            #pragma unroll
            for (int i = 0; i < 4; ++i) {
                int row = m0 + wr + m * 16 + l4 + i;
                float v = acc[m][n][i] + bn + (biasM ? biasM[row] : 0.f);
                C[(size_t)row * ldc + coloff + col] = f2bf(v);
            }
        }
    }
}

__device__ __forceinline__ void epilogue_f32(float* __restrict__ C, int ldc, float scale,
                                             const f32x4 (&acc)[4][4],
                                             const float* __restrict__ bias1) {
    const int tid = threadIdx.x, lane = tid & 63, wv = tid >> 6;
    const int wr = (wv >> 1) * 64, wc = (wv & 1) * 64;
    const int m0 = blockIdx.y * 128, n0 = blockIdx.x * 128;
    const int l15 = lane & 15, l4 = (lane >> 4) * 4;
    #pragma unroll
    for (int m = 0; m < 4; ++m) {
        #pragma unroll
        for (int n = 0; n < 4; ++n) {
            int col = n0 + wc + n * 16 + l15;
            float bn = bias1 ? bias1[col] : 0.f;
            #pragma unroll
            for (int i = 0; i < 4; ++i) {
                int row = m0 + wr + m * 16 + l4 + i;
                C[(size_t)row * ldc + col] = acc[m][n][i] * scale + bn;
            }
        }
    }
}

// ---------------- GEMM wrapper kernels ----------------
// WvfT_e = (Wv_e @ Wff_e)^T : C[d2][d] = sum_h WffT[d2][h] * Wv[d][h]
__global__ __launch_bounds__(256) void mfma_wvf(const u16* __restrict__ WffT,
        const u16* __restrict__ WvB, const int* __restrict__ sel_need,
        u16* __restrict__ WvfT) {
    int e = blockIdx.z;
    if (!sel_need[8 + e]) return;
    const u16* A = WffT + ((size_t)e << 20);
    const u16* B = WvB + ((size_t)e << 20);
    f32x4 acc[4][4]; zero_acc(acc);
    gemm_ds(A, A, 1024, 1024, B, B, 1024, 1024, 1024, acc);
    epilogue_bf16(WvfT + ((size_t)e << 20), 1024, 0, acc, nullptr, nullptr);
}

// c1[e][d2] = sum_h bv[e][h] * Wff[e][h][d2]
__global__ __launch_bounds__(256) void c1_kernel(const float* __restrict__ Wff,
        const float* __restrict__ bv, const int* __restrict__ sel_need,
        float* __restrict__ c1) {
    int e = blockIdx.y;
    if (!sel_need[8 + e]) return;
    __shared__ float bvs[1024];
    int t = threadIdx.x;
    int d = blockIdx.x * 256 + t;
    #pragma unroll
    for (int j = 0; j < 4; ++j) bvs[t + j * 256] = bv[e * 1024 + t + j * 256];
    __syncthreads();
    float s = 0.f;
    const float* W = Wff + ((size_t)e << 20) + d;
    for (int h = 0; h < 1024; ++h) s += bvs[h] * W[(size_t)h * 1024];
    c1[e * 1024 + d] = s;
}

// ybias[b][d] = 2*(c1[e0]+c1[e1])[d] + bff[e0][d] + bff[e1][d]
__global__ __launch_bounds__(256) void ybias_kernel(const float* __restrict__ c1,
        const float* __restrict__ bff, const int* __restrict__ sel,
        float* __restrict__ ybias) {
    int b = blockIdx.y;
    int d = blockIdx.x * 256 + threadIdx.x;
    int e0 = sel[b * 2], e1 = sel[b * 2 + 1];
    ybias[b * 1024 + d] = 2.f * (c1[e0 * 1024 + d] + c1[e1 * 1024 + d])
                        + bff[e0 * 1024 + d] + bff[e1 * 1024 + d];
}

// z<4: Mt_b = Wvf_sum^T X^T (K=2048, long blocks first); z>=4: Q/K projections
__global__ __launch_bounds__(256) void mfma_qk_mt(const u16* __restrict__ Xb,
        const u16* __restrict__ WqT, const u16* __restrict__ WkT,
        const u16* __restrict__ WvfT,
        const float* __restrict__ bq, const float* __restrict__ bk,
        const int* __restrict__ sel, u16* __restrict__ Qb, u16* __restrict__ Kb,
        u16* __restrict__ Mt) {
    int z = blockIdx.z;
    f32x4 acc[4][4]; zero_acc(acc);
    if (z < 4) {
        int b = z;
        int e0 = sel[b * 2], e1 = sel[b * 2 + 1];
        const u16* Xp = Xb + ((size_t)b << 20);
        gemm_ds(WvfT + ((size_t)e0 << 20), WvfT + ((size_t)e1 << 20), 1024, 1024,
                Xp, Xp, 1024, 1024, 2048, acc);
        epilogue_bf16(Mt + ((size_t)b << 20), 1024, 0, acc, nullptr, nullptr);
    } else {
        int zz = z - 4, w = zz >> 3, bs = zz & 7;
        int b = bs >> 1, e = sel[bs];
        const u16* A = Xb + ((size_t)b << 20);
        const u16* B = (w ? WkT : WqT) + ((size_t)e << 20);
        gemm_ds(A, A, 1024, 1024, B, B, 1024, 1024, 1024, acc);
        epilogue_bf16((w ? Kb : Qb) + ((size_t)bs << 20), 1024, 0, acc,
                      (w ? bk : bq) + e * 1024, nullptr);
    }
}

__global__ __launch_bounds__(256) void mfma_scores(const u16* __restrict__ Qb,
        const u16* __restrict__ Kb, float* __restrict__ S) {
    int bs = blockIdx.z;
    const u16* A = Qb + ((size_t)bs << 20);
    const u16* B = Kb + ((size_t)bs << 20);
    f32x4 acc[4][4]; zero_acc(acc);
    gemm_ds(A, A, 1024, 1024, B, B, 1024, 1024, 1024, acc);
    f32x4 sacc[4][4];
    #pragma unroll
    for (int m = 0; m < 4; ++m)
        #pragma unroll
        for (int n = 0; n < 4; ++n) sacc[m][n] = acc[m][n];
    epilogue_f32(S + ((size_t)bs << 20), 1024, SCALE_QK, sacc, nullptr);
}

// A[b][s][t] = softmax(S[b,0]) + softmax(S[b,1])  -> bf16
__global__ __launch_bounds__(256) void sm_combine(const float* __restrict__ S, u16* __restrict__ Ab) {
    int bs = blockIdx.x, b = bs >> 10, s = bs & 1023;
    const float* S0 = S + ((size_t)(b * 2) << 20) + (size_t)s * 1024;
    const float* S1 = S0 + (1u << 20);
    int t = threadIdx.x, lane = t & 63, wv = t >> 6;
    float4 x0 = *(const float4*)(S0 + t * 4);
    float4 x1 = *(const float4*)(S1 + t * 4);
    float m0 = fmaxf(fmaxf(x0.x, x0.y), fmaxf(x0.z, x0.w));
    float m1 = fmaxf(fmaxf(x1.x, x1.y), fmaxf(x1.z, x1.w));
    #pragma unroll
    for (int off = 32; off; off >>= 1) {
        m0 = fmaxf(m0, __shfl_xor(m0, off, 64));
        m1 = fmaxf(m1, __shfl_xor(m1, off, 64));
    }
    __shared__ float wred[4][4];
    if (lane == 0) { wred[wv][0] = m0; wred[wv][1] = m1; }
    __syncthreads();
    m0 = fmaxf(fmaxf(wred[0][0], wred[1][0]), fmaxf(wred[2][0], wred[3][0]));
    m1 = fmaxf(fmaxf(wred[0][1], wred[1][1]), fmaxf(wred[2][1], wred[3][1]));
    float4 e0, e1;
    e0.x = __expf(x0.x - m0); e0.y = __expf(x0.y - m0); e0.z = __expf(x0.z - m0); e0.w = __expf(x0.w - m0);
    e1.x = __expf(x1.x - m1); e1.y = __expf(x1.y - m1); e1.z = __expf(x1.z - m1); e1.w = __expf(x1.w - m1);
    float s0 = e0.x + e0.y + e0.z + e0.w;
    float s1 = e1.x + e1.y + e1.z + e1.w;
    #pragma unroll
    for (int off = 32; off; off >>= 1) {
        s0 += __shfl_xor(s0, off, 64);
        s1 += __shfl_xor(s1, off, 64);
    }
    if (lane == 0) { wred[wv][2] = s0; wred[wv][3] = s1; }
    __syncthreads();
    s0 = wred[0][2] + wred[1][2] + wred[2][2] + wred[3][2];
    s1 = wred[0][3] + wred[1][3] + wred[2][3] + wred[3][3];
    float r0 = 1.f / s0, r1 = 1.f / s1;
    us4 o;
    o[0] = f2bf(e0.x * r0 + e1.x * r1); o[1] = f2bf(e0.y * r0 + e1.y * r1);
    o[2] = f2bf(e0.z * r0 + e1.z * r1); o[3] = f2bf(e0.w * r0 + e1.w * r1);
    *(us4*)(Ab + ((size_t)b << 20) + (size_t)s * 1024 + t * 4) = o;
}

// y[b][s][d2] = sum_t A[b][s][t] * Mt[b][d2][t] + ybias[b][d2]
__global__ __launch_bounds__(256) void mfma_y(const u16* __restrict__ Abf,
        const u16* __restrict__ Mt, const float* __restrict__ ybias,
        float* __restrict__ y) {
    int b = blockIdx.z;
    const u16* A = Abf + ((size_t)b << 20);
    const u16* B = Mt + ((size_t)b << 20);
    f32x4 acc[4][4]; zero_acc(acc);
    gemm_ds(A, A, 1024, 1024, B, B, 1024, 1024, 1024, acc);
    epilogue_f32(y + ((size_t)b << 20), 1024, 1.0f, acc, ybias + b * 1024);
}

// ---------------- launcher ----------------
extern "C" void kernel_launch(void* const* d_in, const int* in_sizes, int n_in,
                              void* d_out, int out_size, void* d_ws, size_t ws_size,
                              hipStream_t stream) {
    const float* X   = (const float*)d_in[0];
    const float* sW  = (const float*)d_in[2];
    const float* sb  = (const float*)d_in[3];
    const float* Wq  = (const float*)d_in[4];
    const float* bq  = (const float*)d_in[5];
    const float* Wk  = (const float*)d_in[6];
    const float* bk  = (const float*)d_in[7];
    const float* Wv  = (const float*)d_in[8];
    const float* bv  = (const float*)d_in[9];
    const float* Wff = (const float*)d_in[10];
    const float* bff = (const float*)d_in[11];
    float* y = (float*)d_out;

    char* w = (char*)d_ws;
    float* part = (float*)w;                       // 128 KB
    int*   sel  = (int*)(w + (1u << 17));          // sel[0..7] + need[8..15]
    u16* base = (u16*)(w + (1u << 18));
    u16* Xb   = base;                              // 4M u16
    u16* WqT  = Xb   + (4u << 20);                 // 8M u16 each
    u16* WkT  = WqT  + (8u << 20);
    u16* WffT = WkT  + (8u << 20);
    u16* WvB  = WffT + (8u << 20);
    u16* WvfT = WvB  + (8u << 20);
    u16* Kb   = WvfT + (8u << 20);
    float* S  = (float*)(Kb + (8u << 20));         // 8M f32 = 32 MB
    float* c1 = S + (8u << 20);                    // 8K f32
    float* ybias = c1 + 8192;                      // 4K f32
    // overlays (lifetime-disjoint):
    u16* Qb  = WvB;     // WvB dead after mfma_wvf; Qb written in mfma_qk_mt
    u16* Mt  = WffT;    // WffT dead after mfma_wvf (c1 reads original Wff)
    u16* Abf = WqT;     // WqT dead after mfma_qk_mt
    // total ws use ~136 MB

    router_partial<<<1024, 256, 0, stream>>>(X, sW, part);
    router_final<<<1, 256, 0, stream>>>(part, sb, sel);
    cvt_x<<<2048, 256, 0, stream>>>(X, Xb);
    cvt_plain<<<dim3(512, 8), 256, 0, stream>>>(Wv, sel, WvB);
    cvt_wt<<<dim3(8, 8, 24), 256, 0, stream>>>(Wq, Wk, Wff, sel, WqT, WkT, WffT);

    mfma_wvf<<<dim3(8, 8, 8), 256, 0, stream>>>(WffT, WvB, sel, WvfT);
    c1_kernel<<<dim3(4, 8), 256, 0, stream>>>(Wff, bv, sel, c1);
    ybias_kernel<<<dim3(4, 4), 256, 0, stream>>>(c1, bff, sel, ybias);

    mfma_qk_mt<<<dim3(8, 8, 20), 256, 0, stream>>>(Xb, WqT, WkT, WvfT, bq, bk, sel, Qb, Kb, Mt);
    mfma_scores<<<dim3(8, 8, 8), 256, 0, stream>>>(Qb, Kb, S);
    sm_combine<<<4096, 256, 0, stream>>>(S, Abf);
    mfma_y<<<dim3(8, 8, 4), 256, 0, stream>>>(Abf, Mt, ybias, y);
}

// Round 5
// 261.968 us; speedup vs baseline: 1.0500x; 1.0500x over previous
//
#include <hip/hip_runtime.h>
#include <math.h>

typedef unsigned short u16;
typedef __attribute__((ext_vector_type(8))) short bffrag;   // 8 bf16 MFMA operand
typedef __attribute__((ext_vector_type(4))) float f32x4;    // MFMA accumulator
typedef __attribute__((ext_vector_type(4))) unsigned short us4;
typedef __attribute__((ext_vector_type(8))) unsigned short us8;

#define SCALE_QK (1.0f/32.0f)

// fp32 -> bf16 round-to-nearest-even (bit trick, NaN-free inputs)
__device__ __forceinline__ u16 f2bf(float f) {
    unsigned u = __builtin_bit_cast(unsigned, f);
    u += 0x7fffu + ((u >> 16) & 1u);
    return (u16)(u >> 16);
}

__device__ __forceinline__ void gld16(const u16* g, u16* l) {
    __builtin_amdgcn_global_load_lds(
        (const __attribute__((address_space(1))) void*)g,
        (__attribute__((address_space(3))) void*)l, 16, 0, 0);
}

// ---------------- router (fp32, exact) ----------------
__global__ __launch_bounds__(256) void router_partial(const float* __restrict__ X,
                                                      const float* __restrict__ sW,
                                                      float* __restrict__ part) {
    float acc[32];
    #pragma unroll
    for (int a = 0; a < 32; ++a) acc[a] = 0.f;
    int tid = blockIdx.x * 256 + threadIdx.x;
    #pragma unroll
    for (int q = 0; q < 4; ++q) {
        int i = tid + q * 262144;
        float4 w0 = *(const float4*)(sW + (size_t)i * 8);
        float4 w1 = *(const float4*)(sW + (size_t)i * 8 + 4);
        #pragma unroll
        for (int b = 0; b < 4; ++b) {
            float x = X[((size_t)b << 20) + i];
            acc[b*8+0] += x * w0.x; acc[b*8+1] += x * w0.y;
            acc[b*8+2] += x * w0.z; acc[b*8+3] += x * w0.w;
            acc[b*8+4] += x * w1.x; acc[b*8+5] += x * w1.y;
            acc[b*8+6] += x * w1.z; acc[b*8+7] += x * w1.w;
        }
    }
    __shared__ float wsum[4][32];
    int lane = threadIdx.x & 63, wv = threadIdx.x >> 6;
    #pragma unroll
    for (int a = 0; a < 32; ++a) {
        float v = acc[a];
        #pragma unroll
        for (int off = 32; off; off >>= 1) v += __shfl_down(v, off, 64);
        if (lane == 0) wsum[wv][a] = v;
    }
    __syncthreads();
    int t = threadIdx.x;
    if (t < 32)
        part[(size_t)t * 1024 + blockIdx.x] = wsum[0][t] + wsum[1][t] + wsum[2][t] + wsum[3][t];
}

__global__ __launch_bounds__(256) void router_final(const float* __restrict__ part,
                                                    const float* __restrict__ sb,
                                                    int* __restrict__ sel_need) {
    __shared__ float ps[32][8];
    __shared__ float lg[32];
    int t = threadIdx.x, a = t >> 3, c = t & 7;
    {
        float s = 0.f;
        const float* p = part + (size_t)a * 1024 + c * 128;
        for (int i = 0; i < 128; ++i) s += p[i];
        ps[a][c] = s;
    }
    __syncthreads();
    if (t < 32) {
        float v = 0.f;
        #pragma unroll
        for (int j = 0; j < 8; ++j) v += ps[t][j];
        lg[t] = v + sb[t & 7];
    }
    __syncthreads();
    if (t < 4) {
        int base = t * 8;
        int e1 = 0; float v1 = lg[base];
        for (int e = 1; e < 8; ++e) { if (lg[base + e] > v1) { v1 = lg[base + e]; e1 = e; } }
        int e2 = -1; float v2 = -INFINITY;
        for (int e = 0; e < 8; ++e) {
            if (e == e1) continue;
            if (lg[base + e] > v2) { v2 = lg[base + e]; e2 = e; }
        }
        sel_need[t * 2] = e1; sel_need[t * 2 + 1] = e2;
    }
    __syncthreads();
    if (t < 8) {
        int need = 0;
        for (int j = 0; j < 8; ++j) need |= (sel_need[j] == t);
        sel_need[8 + t] = need;
    }
}

// ---------------- converts ----------------
__global__ __launch_bounds__(256) void cvt_x(const float* __restrict__ X, u16* __restrict__ Xb) {
    size_t i = (size_t)(blockIdx.x * 256 + threadIdx.x) * 8;
    float4 a = *(const float4*)(X + i);
    float4 b = *(const float4*)(X + i + 4);
    us8 o;
    o[0] = f2bf(a.x); o[1] = f2bf(a.y); o[2] = f2bf(a.z); o[3] = f2bf(a.w);
    o[4] = f2bf(b.x); o[5] = f2bf(b.y); o[6] = f2bf(b.z); o[7] = f2bf(b.w);
    *(us8*)(Xb + i) = o;
}

__global__ __launch_bounds__(256) void cvt_plain(const float* __restrict__ src,
                                                 const int* __restrict__ sel_need,
                                                 u16* __restrict__ dst) {
    int e = blockIdx.y;
    if (!sel_need[8 + e]) return;
    size_t i = ((size_t)e << 20) + (size_t)(blockIdx.x * 256 + threadIdx.x) * 8;
    float4 a = *(const float4*)(src + i);
    float4 b = *(const float4*)(src + i + 4);
    us8 o;
    o[0] = f2bf(a.x); o[1] = f2bf(a.y); o[2] = f2bf(a.z); o[3] = f2bf(a.w);
    o[4] = f2bf(b.x); o[5] = f2bf(b.y); o[6] = f2bf(b.z); o[7] = f2bf(b.w);
    *(us8*)(dst + i) = o;
}

// transpose + convert 1024x1024: z 0..23 = Wq/Wk/Wff expert matrices (need-gated),
// z 24..27 = X batch b (always)
__global__ __launch_bounds__(256) void cvt_wt(const float* __restrict__ Wq,
                                              const float* __restrict__ Wk,
                                              const float* __restrict__ Wff,
                                              const float* __restrict__ X,
                                              const int* __restrict__ sel_need,
                                              u16* __restrict__ WqT, u16* __restrict__ WkT,
                                              u16* __restrict__ WffT, u16* __restrict__ XbT) {
    int z = blockIdx.z;
    int type = z >> 3, e = z & 7;
    const float* src;
    u16* dst;
    if (type < 3) {
        if (!sel_need[8 + e]) return;
        src = (type == 0 ? Wq : type == 1 ? Wk : Wff) + ((size_t)e << 20);
        dst = (type == 0 ? WqT : type == 1 ? WkT : WffT) + ((size_t)e << 20);
    } else {
        int b = z & 3;
        src = X + ((size_t)b << 20);
        dst = XbT + ((size_t)b << 20);
    }
    __shared__ u16 lt[128 * 136];
    int R0 = blockIdx.y * 128, C0 = blockIdx.x * 128;
    int t = threadIdx.x;
    int c = t & 127;
    int rh = (t >> 7) * 4;
    #pragma unroll
    for (int it = 0; it < 16; ++it) {
        int r4 = it * 8 + rh;
        us4 o;
        #pragma unroll
        for (int j = 0; j < 4; ++j)
            o[j] = f2bf(src[(size_t)(R0 + r4 + j) * 1024 + C0 + c]);
        *(us4*)&lt[c * 136 + r4] = o;
    }
    __syncthreads();
    int dd = (t & 15) * 8;
    int hh = t >> 4;
    #pragma unroll
    for (int it = 0; it < 8; ++it) {
        int cr = it * 16 + hh;
        us8 o = *(const us8*)&lt[cr * 136 + dd];
        *(us8*)(dst + (size_t)(C0 + cr) * 1024 + R0 + dd) = o;
    }
}

// ============ 8-phase 256x256 MFMA core (T2+T3+T4+T5) ============
// C[m][n] = sum_k A[m][k]*B[n][k].  8 waves (2M x 4N), BK=64, 128 KB LDS dbuf.
// LDS layout per buf: A region 256x64 u16 (16384), B region same. Swizzle:
// 16B slot j within a row XOR'd with (row&7), applied on BOTH the global source
// of global_load_lds (linear dest) and the ds_read address (rule 21).
__device__ __forceinline__ void stage_half8(const u16* g, int ld, u16* ldst, int tid) {
    int r = tid >> 3;
    int j = ((tid ^ r) & 7) * 8;
    gld16(g + (size_t)r * ld + j, ldst + tid * 8);
    gld16(g + (size_t)(r + 64) * ld + j, ldst + 4096 + tid * 8);
}

template<int Q, bool LASTVM>
__device__ __forceinline__ void phase8(const u16* Ac, const bffrag (&bfr)[4][2],
                                       f32x4 (&acc)[8][4], int rb, int l15, int x0,
                                       const u16* sg, int sld, u16* sdst, int tid) {
    bffrag af[2][2];
    #pragma unroll
    for (int mm = 0; mm < 2; ++mm) {
        int r = (rb + Q * 32 + mm * 16 + l15) * 64;
        af[mm][0] = *(const bffrag*)(Ac + r + x0);
        af[mm][1] = *(const bffrag*)(Ac + r + (x0 ^ 32));
    }
    __builtin_amdgcn_sched_barrier(0);
    stage_half8(sg, sld, sdst, tid);
    __builtin_amdgcn_sched_barrier(0);
    __builtin_amdgcn_s_barrier();
    asm volatile("s_waitcnt lgkmcnt(0)" ::: "memory");
    __builtin_amdgcn_sched_barrier(0);
    __builtin_amdgcn_s_setprio(1);
    #pragma unroll
    for (int ks = 0; ks < 2; ++ks)
        #pragma unroll
        for (int mm = 0; mm < 2; ++mm)
            #pragma unroll
            for (int nn = 0; nn < 4; ++nn)
                acc[Q*2+mm][nn] = __builtin_amdgcn_mfma_f32_16x16x32_bf16(
                    af[mm][ks], bfr[nn][ks], acc[Q*2+mm][nn], 0, 0, 0);
    __builtin_amdgcn_s_setprio(0);
    __builtin_amdgcn_sched_barrier(0);
    if (LASTVM) asm volatile("s_waitcnt vmcnt(4)" ::: "memory");
    __builtin_amdgcn_s_barrier();
}

__device__ __forceinline__ void gemm8(const u16* __restrict__ A, int lda,
                                      const u16* __restrict__ B, int ldb,
                                      int K, f32x4 (&acc)[8][4]) {
    __shared__ u16 lds[65536];                 // 128 KB: [buf][A 16384 | B 16384]
    const int tid = threadIdx.x, l = tid & 63, wid = tid >> 6;
    const int wr = wid >> 2, wc = wid & 3;
    const int l15 = l & 15;
    const int rb = wr * 128;                   // wave A-row base
    const int cb = wc * 64;                    // wave B-row base
    const int x0 = (((l >> 4) ^ (l & 7)) * 8); // swizzled k-slot, ks=0 (ks=1: ^32)
    const int m0 = blockIdx.y * 256, n0 = blockIdx.x * 256;
    const int nt = K >> 6;

    const u16* Ag = A + (size_t)m0 * lda;
    const u16* Bg = B + (size_t)n0 * ldb;

    // prologue: A(0) halves -> buf0, B(0) -> buf0, B(1) -> buf1
    stage_half8(Ag,                          lda, lds,                 tid);
    stage_half8(Ag + (size_t)128 * lda,      lda, lds + 8192,          tid);
    stage_half8(Bg,                          ldb, lds + 16384,         tid);
    stage_half8(Bg + (size_t)128 * ldb,      ldb, lds + 16384 + 8192,  tid);
    stage_half8(Bg + 64,                     ldb, lds + 32768 + 16384, tid);
    stage_half8(Bg + 64 + (size_t)128 * ldb, ldb, lds + 32768 + 16384 + 8192, tid);
    asm volatile("s_waitcnt vmcnt(4)" ::: "memory");
    __builtin_amdgcn_s_barrier();

    for (int t7 = 0; t7 < nt; ++t7) {
        const int cur = t7 & 1;
        u16* Ac = lds + cur * 32768;
        u16* Bc = Ac + 16384;
        u16* An = lds + (cur ^ 1) * 32768;
        const int ka = (t7 + 1 < nt ? t7 + 1 : nt - 1) << 6;   // A(kt+1) col off
        const int kb = (t7 + 2 < nt ? t7 + 2 : nt - 1) << 6;   // B(kt+2) col off
        const u16* sA0 = Ag + ka;
        const u16* sA1 = Ag + (size_t)128 * lda + ka;
        const u16* sB0 = Bg + kb;
        const u16* sB1 = Bg + (size_t)128 * ldb + kb;

        // B-frags for this K-tile (read in phase 0, used by all 4 phases)
        bffrag bfr[4][2];
        #pragma unroll
        for (int nn = 0; nn < 4; ++nn) {
            int r = (cb + nn * 16 + l15) * 64;
            bfr[nn][0] = *(const bffrag*)(Bc + r + x0);
            bfr[nn][1] = *(const bffrag*)(Bc + r + (x0 ^ 32));
        }
        phase8<0, false>(Ac, bfr, acc, rb, l15, x0, sA0, lda, An, tid);
        phase8<1, false>(Ac, bfr, acc, rb, l15, x0, sA1, lda, An + 8192, tid);
        phase8<2, false>(Ac, bfr, acc, rb, l15, x0, sB0, ldb, Bc, tid);
        phase8<3, true >(Ac, bfr, acc, rb, l15, x0, sB1, ldb, Bc + 8192, tid);
    }
}

__device__ __forceinline__ void zero8(f32x4 (&acc)[8][4]) {
    #pragma unroll
    for (int m = 0; m < 8; ++m)
        #pragma unroll
        for (int n = 0; n < 4; ++n)
            #pragma unroll
            for (int i = 0; i < 4; ++i) acc[m][n][i] = 0.f;
}

__device__ __forceinline__ void epi8_bf16(u16* __restrict__ C, int ldc,
                                          const f32x4 (&acc)[8][4],
                                          const float* __restrict__ biasN) {
    const int tid = threadIdx.x, l = tid & 63, wid = tid >> 6;
    const int wr = wid >> 2, wc = wid & 3;
    const int m0 = blockIdx.y * 256 + wr * 128, n0 = blockIdx.x * 256 + wc * 64;
    const int l15 = l & 15, l4 = (l >> 4) * 4;
    #pragma unroll
    for (int mt = 0; mt < 8; ++mt)
        #pragma unroll
        for (int nn = 0; nn < 4; ++nn) {
            int col = n0 + nn * 16 + l15;
            float bn = biasN ? biasN[col] : 0.f;
            #pragma unroll
            for (int i = 0; i < 4; ++i) {
                int row = m0 + mt * 16 + l4 + i;
                C[(size_t)row * ldc + col] = f2bf(acc[mt][nn][i] + bn);
            }
        }
}

__device__ __forceinline__ void epi8_f32(float* __restrict__ C, int ldc, float scale,
                                         const f32x4 (&acc)[8][4]) {
    const int tid = threadIdx.x, l = tid & 63, wid = tid >> 6;
    const int wr = wid >> 2, wc = wid & 3;
    const int m0 = blockIdx.y * 256 + wr * 128, n0 = blockIdx.x * 256 + wc * 64;
    const int l15 = l & 15, l4 = (l >> 4) * 4;
    #pragma unroll
    for (int mt = 0; mt < 8; ++mt)
        #pragma unroll
        for (int nn = 0; nn < 4; ++nn) {
            int col = n0 + nn * 16 + l15;
            #pragma unroll
            for (int i = 0; i < 4; ++i) {
                int row = m0 + mt * 16 + l4 + i;
                C[(size_t)row * ldc + col] = acc[mt][nn][i] * scale;
            }
        }
}

// D1: z 0..15, w=z>>3 (0=Q,1=K), bs=z&7
__global__ __launch_bounds__(512) void mfma8_qk(const u16* __restrict__ Xb,
        const u16* __restrict__ WqT, const u16* __restrict__ WkT,
        const float* __restrict__ bq, const float* __restrict__ bk,
        const int* __restrict__ sel, u16* __restrict__ Qb, u16* __restrict__ Kb) {
    int z = blockIdx.z, w = z >> 3, bs = z & 7;
    int b = bs >> 1, e = sel[bs];
    f32x4 acc[8][4]; zero8(acc);
    gemm8(Xb + ((size_t)b << 20), 1024, (w ? WkT : WqT) + ((size_t)e << 20), 1024, 1024, acc);
    epi8_bf16((w ? Kb : Qb) + ((size_t)bs << 20), 1024, acc, (w ? bk : bq) + e * 1024);
}

// D2: z<8 scores(bs=z); z 8..11 wvf half0 (b=z-8); z 12..15 wvf half1
__global__ __launch_bounds__(512) void mfma8_sw(const u16* __restrict__ Qb,
        const u16* __restrict__ Kb, const u16* __restrict__ WffT,
        const u16* __restrict__ WvB, const int* __restrict__ sel,
        float* __restrict__ S, float* __restrict__ P0, float* __restrict__ P1) {
    int z = blockIdx.z;
    f32x4 acc[8][4]; zero8(acc);
    if (z < 8) {
        gemm8(Qb + ((size_t)z << 20), 1024, Kb + ((size_t)z << 20), 1024, 1024, acc);
        epi8_f32(S + ((size_t)z << 20), 1024, SCALE_QK, acc);
    } else {
        int h = (z >= 12), b = z & 3, e = sel[b * 2 + h];
        gemm8(WffT + ((size_t)e << 20), 1024, WvB + ((size_t)e << 20), 1024, 1024, acc);
        epi8_f32((h ? P1 : P0) + ((size_t)b << 20), 1024, 1.0f, acc);
    }
}

// Wvfsum[b] = bf16(P0[b] + P1[b])
__global__ __launch_bounds__(256) void wvfadd(const float* __restrict__ P0,
                                              const float* __restrict__ P1,
                                              u16* __restrict__ W) {
    size_t i = (size_t)(blockIdx.x * 256 + threadIdx.x) * 8;
    float4 a0 = *(const float4*)(P0 + i),     a1 = *(const float4*)(P0 + i + 4);
    float4 b0 = *(const float4*)(P1 + i),     b1 = *(const float4*)(P1 + i + 4);
    us8 o;
    o[0] = f2bf(a0.x + b0.x); o[1] = f2bf(a0.y + b0.y);
    o[2] = f2bf(a0.z + b0.z); o[3] = f2bf(a0.w + b0.w);
    o[4] = f2bf(a1.x + b1.x); o[5] = f2bf(a1.y + b1.y);
    o[6] = f2bf(a1.z + b1.z); o[7] = f2bf(a1.w + b1.w);
    *(us8*)(W + i) = o;
}

// ---------------- 2-phase 128x128 core (small tail GEMMs) ----------------
__device__ __forceinline__ void stage_tile(const u16* a0, const u16* a1,
                                           const u16* b0, const u16* b1,
                                           u16* sa, u16* sb, int tid) {
    gld16(a0, &sa[tid * 8]);
    gld16(a1, &sa[2048 + tid * 8]);
    gld16(b0, &sb[tid * 8]);
    gld16(b1, &sb[2048 + tid * 8]);
}

__device__ __forceinline__ void gemm_ds(const u16* __restrict__ A, int lda,
                                        const u16* __restrict__ B, int ldb,
                                        int K, f32x4 (&acc)[4][4]) {
    __shared__ u16 sA[2][4096];
    __shared__ u16 sB[2][4096];
    const int tid = threadIdx.x, lane = tid & 63, wv = tid >> 6;
    const int wr = (wv >> 1) * 64, wc = (wv & 1) * 64;
    const int l15 = lane & 15, lk = (lane >> 4) * 8;
    const int m0 = blockIdx.y * 128, n0 = blockIdx.x * 128;
    const int r0 = tid >> 2, k8 = (tid & 3) * 8;

    const u16* a0 = A + (size_t)(m0 + r0) * lda + k8;
    const u16* a1 = A + (size_t)(m0 + 64 + r0) * lda + k8;
    const u16* b0 = B + (size_t)(n0 + r0) * ldb + k8;
    const u16* b1 = B + (size_t)(n0 + 64 + r0) * ldb + k8;

    stage_tile(a0, a1, b0, b1, sA[0], sB[0], tid);
    __syncthreads();

    const int nt = K >> 5;
    for (int t = 0; t < nt; ++t) {
        const int cur = t & 1;
        if (t + 1 < nt) {
            int k0 = (t + 1) << 5;
            stage_tile(a0 + k0, a1 + k0, b0 + k0, b1 + k0, sA[cur ^ 1], sB[cur ^ 1], tid);
        }
        bffrag av[4], bf[4];
        #pragma unroll
        for (int m = 0; m < 4; ++m)
            av[m] = *reinterpret_cast<const bffrag*>(&sA[cur][(wr + m * 16 + l15) * 32 + lk]);
        #pragma unroll
        for (int n = 0; n < 4; ++n)
            bf[n] = *reinterpret_cast<const bffrag*>(&sB[cur][(wc + n * 16 + l15) * 32 + lk]);
        #pragma unroll
        for (int m = 0; m < 4; ++m)
            #pragma unroll
            for (int n = 0; n < 4; ++n)
                acc[m][n] = __builtin_amdgcn_mfma_f32_16x16x32_bf16(av[m], bf[n], acc[m][n], 0, 0, 0);
        __syncthreads();
    }
}

__device__ __forceinline__ void zero_acc(f32x4 (&acc)[4][4]) {
    #pragma unroll
    for (int m = 0; m < 4; ++m)
        #pragma unroll
        for (int n = 0; n < 4; ++n)
            #pragma unroll
            for (int i = 0; i < 4; ++i) acc[m][n][i] = 0.f;
}

__device__ __forceinline__ void epilogue_bf16(u16* __restrict__ C, int ldc,
                                              const f32x4 (&acc)[4][4]) {
    const int tid = threadIdx.x, lane = tid & 63, wv = tid >> 6;
    const int wr = (wv >> 1) * 64, wc = (wv & 1) * 64;
    const int m0 = blockIdx.y * 128, n0 = blockIdx.x * 128;
    const int l15 = lane & 15, l4 = (lane >> 4) * 4;
    #pragma unroll
    for (int m = 0; m < 4; ++m)
        #pragma unroll
        for (int n = 0; n < 4; ++n) {
            int col = n0 + wc + n * 16 + l15;
            #pragma unroll
            for (int i = 0; i < 4; ++i) {
                int row = m0 + wr + m * 16 + l4 + i;
                C[(size_t)row * ldc + col] = f2bf(acc[m][n][i]);
            }
        }
}

__device__ __forceinline__ void epilogue_f32(float* __restrict__ C, int ldc,
                                             const f32x4 (&acc)[4][4],
                                             const float* __restrict__ bias1) {
    const int tid = threadIdx.x, lane = tid & 63, wv = tid >> 6;
    const int wr = (wv >> 1) * 64, wc = (wv & 1) * 64;
    const int m0 = blockIdx.y * 128, n0 = blockIdx.x * 128;
    const int l15 = lane & 15, l4 = (lane >> 4) * 4;
    #pragma unroll
    for (int m = 0; m < 4; ++m)
        #pragma unroll
        for (int n = 0; n < 4; ++n) {
            int col = n0 + wc + n * 16 + l15;
            float bn = bias1 ? bias1[col] : 0.f;
            #pragma unroll
            for (int i = 0; i < 4; ++i) {
                int row = m0 + wr + m * 16 + l4 + i;
                C[(size_t)row * ldc + col] = acc[m][n][i] + bn;
            }
        }
}

// c1[e][d2] = sum_h bv[e][h] * Wff[e][h][d2]
__global__ __launch_bounds__(256) void c1_kernel(const float* __restrict__ Wff,
        const float* __restrict__ bv, const int* __restrict__ sel_need,
        float* __restrict__ c1) {
    int e = blockIdx.y;
    if (!sel_need[8 + e]) return;
    __shared__ float bvs[1024];
    int t = threadIdx.x;
    int d = blockIdx.x * 256 + t;
    #pragma unroll
    for (int j = 0; j < 4; ++j) bvs[t + j * 256] = bv[e * 1024 + t + j * 256];
    __syncthreads();
    float s = 0.f;
    const float* W = Wff + ((size_t)e << 20) + d;
    for (int h = 0; h < 1024; ++h) s += bvs[h] * W[(size_t)h * 1024];
    c1[e * 1024 + d] = s;
}

__global__ __launch_bounds__(256) void ybias_kernel(const float* __restrict__ c1,
        const float* __restrict__ bff, const int* __restrict__ sel,
        float* __restrict__ ybias) {
    int b = blockIdx.y;
    int d = blockIdx.x * 256 + threadIdx.x;
    int e0 = sel[b * 2], e1 = sel[b * 2 + 1];
    ybias[b * 1024 + d] = 2.f * (c1[e0 * 1024 + d] + c1[e1 * 1024 + d])
                        + bff[e0 * 1024 + d] + bff[e1 * 1024 + d];
}

// A[b][s][t] = softmax(S[b,0]) + softmax(S[b,1])  -> bf16
__global__ __launch_bounds__(256) void sm_combine(const float* __restrict__ S, u16* __restrict__ Ab) {
    int bs = blockIdx.x, b = bs >> 10, s = bs & 1023;
    const float* S0 = S + ((size_t)(b * 2) << 20) + (size_t)s * 1024;
    const float* S1 = S0 + (1u << 20);
    int t = threadIdx.x, lane = t & 63, wv = t >> 6;
    float4 x0 = *(const float4*)(S0 + t * 4);
    float4 x1 = *(const float4*)(S1 + t * 4);
    float m0 = fmaxf(fmaxf(x0.x, x0.y), fmaxf(x0.z, x0.w));
    float m1 = fmaxf(fmaxf(x1.x, x1.y), fmaxf(x1.z, x1.w));
    #pragma unroll
    for (int off = 32; off; off >>= 1) {
        m0 = fmaxf(m0, __shfl_xor(m0, off, 64));
        m1 = fmaxf(m1, __shfl_xor(m1, off, 64));
    }
    __shared__ float wred[4][4];
    if (lane == 0) { wred[wv][0] = m0; wred[wv][1] = m1; }
    __syncthreads();
    m0 = fmaxf(fmaxf(wred[0][0], wred[1][0]), fmaxf(wred[2][0], wred[3][0]));
    m1 = fmaxf(fmaxf(wred[0][1], wred[1][1]), fmaxf(wred[2][1], wred[3][1]));
    float4 e0, e1;
    e0.x = __expf(x0.x - m0); e0.y = __expf(x0.y - m0); e0.z = __expf(x0.z - m0); e0.w = __expf(x0.w - m0);
    e1.x = __expf(x1.x - m1); e1.y = __expf(x1.y - m1); e1.z = __expf(x1.z - m1); e1.w = __expf(x1.w - m1);
    float s0 = e0.x + e0.y + e0.z + e0.w;
    float s1 = e1.x + e1.y + e1.z + e1.w;
    #pragma unroll
    for (int off = 32; off; off >>= 1) {
        s0 += __shfl_xor(s0, off, 64);
        s1 += __shfl_xor(s1, off, 64);
    }
    if (lane == 0) { wred[wv][2] = s0; wred[wv][3] = s1; }
    __syncthreads();
    s0 = wred[0][2] + wred[1][2] + wred[2][2] + wred[3][2];
    s1 = wred[0][3] + wred[1][3] + wred[2][3] + wred[3][3];
    float r0 = 1.f / s0, r1 = 1.f / s1;
    us4 o;
    o[0] = f2bf(e0.x * r0 + e1.x * r1); o[1] = f2bf(e0.y * r0 + e1.y * r1);
    o[2] = f2bf(e0.z * r0 + e1.z * r1); o[3] = f2bf(e0.w * r0 + e1.w * r1);
    *(us4*)(Ab + ((size_t)b << 20) + (size_t)s * 1024 + t * 4) = o;
}

// AX[b][s][d] = sum_t A[b][s][t] * X[b][t][d]   (B-operand = XbT[d][t])
__global__ __launch_bounds__(256) void mfma_ax(const u16* __restrict__ Abf,
        const u16* __restrict__ XbT, u16* __restrict__ AXbf) {
    int b = blockIdx.z;
    f32x4 acc[4][4]; zero_acc(acc);
    gemm_ds(Abf + ((size_t)b << 20), 1024, XbT + ((size_t)b << 20), 1024, 1024, acc);
    epilogue_bf16(AXbf + ((size_t)b << 20), 1024, acc);
}

// y[b][s][d2] = sum_d AX[b][s][d] * Wvfsum[b][d2][d] + ybias[b][d2]
__global__ __launch_bounds__(256) void mfma_y(const u16* __restrict__ AXbf,
        const u16* __restrict__ Wvfsum, const float* __restrict__ ybias,
        float* __restrict__ y) {
    int b = blockIdx.z;
    f32x4 acc[4][4]; zero_acc(acc);
    gemm_ds(AXbf + ((size_t)b << 20), 1024, Wvfsum + ((size_t)b << 20), 1024, 1024, acc);
    epilogue_f32(y + ((size_t)b << 20), 1024, acc, ybias + b * 1024);
}

// ---------------- launcher ----------------
extern "C" void kernel_launch(void* const* d_in, const int* in_sizes, int n_in,
                              void* d_out, int out_size, void* d_ws, size_t ws_size,
                              hipStream_t stream) {
    const float* X   = (const float*)d_in[0];
    const float* sW  = (const float*)d_in[2];
    const float* sb  = (const float*)d_in[3];
    const float* Wq  = (const float*)d_in[4];
    const float* bq  = (const float*)d_in[5];
    const float* Wk  = (const float*)d_in[6];
    const float* bk  = (const float*)d_in[7];
    const float* Wv  = (const float*)d_in[8];
    const float* bv  = (const float*)d_in[9];
    const float* Wff = (const float*)d_in[10];
    const float* bff = (const float*)d_in[11];
    float* y = (float*)d_out;

    char* w = (char*)d_ws;
    float* part  = (float*)w;                  // 128 KB (dead after router_final)
    float* c1    = (float*)w;                  // overlay of part (written after)
    float* ybias = (float*)(w + 65536);        // overlay of part upper half
    int*   sel   = (int*)(w + 131072);
    u16* base = (u16*)(w + (1u << 18));
    u16* Xb   = base;                          // 8 MB   [Wvfsum overlay]
    u16* XbT  = Xb   + (4u << 20);             // 8 MB
    u16* WqT  = XbT  + (4u << 20);             // 16 MB  [Abf overlay]
    u16* WkT  = WqT  + (8u << 20);             // 16 MB  [AXbf overlay]
    u16* WffT = WkT  + (8u << 20);             // 16 MB
    u16* WvB  = WffT + (8u << 20);             // 16 MB
    u16* Qb   = WvB  + (8u << 20);             // 16 MB
    u16* Kb   = Qb   + (8u << 20);             // 16 MB
    float* S  = (float*)(Kb + (8u << 20));     // 32 MB
    float* P0 = S  + (8u << 20);               // 16 MB
    float* P1 = P0 + (4u << 20);               // 16 MB
    u16* Wvfsum = Xb;    // Xb dead after mfma8_qk
    u16* Abf    = WqT;   // WqT dead after mfma8_qk
    u16* AXbf   = WkT;   // WkT dead after mfma8_qk

    router_partial<<<1024, 256, 0, stream>>>(X, sW, part);
    router_final<<<1, 256, 0, stream>>>(part, sb, sel);
    c1_kernel<<<dim3(4, 8), 256, 0, stream>>>(Wff, bv, sel, c1);
    ybias_kernel<<<dim3(4, 4), 256, 0, stream>>>(c1, bff, sel, ybias);
    cvt_x<<<2048, 256, 0, stream>>>(X, Xb);
    cvt_plain<<<dim3(512, 8), 256, 0, stream>>>(Wv, sel, WvB);
    cvt_wt<<<dim3(8, 8, 28), 256, 0, stream>>>(Wq, Wk, Wff, X, sel, WqT, WkT, WffT, XbT);

    mfma8_qk<<<dim3(4, 4, 16), 512, 0, stream>>>(Xb, WqT, WkT, bq, bk, sel, Qb, Kb);
    mfma8_sw<<<dim3(4, 4, 16), 512, 0, stream>>>(Qb, Kb, WffT, WvB, sel, S, P0, P1);
    wvfadd<<<2048, 256, 0, stream>>>(P0, P1, Wvfsum);
    sm_combine<<<4096, 256, 0, stream>>>(S, Abf);
    mfma_ax<<<dim3(8, 8, 4), 256, 0, stream>>>(Abf, XbT, AXbf);
    mfma_y<<<dim3(8, 8, 4), 256, 0, stream>>>(AXbf, Wvfsum, ybias, y);
}

// Round 6
// 239.078 us; speedup vs baseline: 1.1505x; 1.0957x over previous
//
#include <hip/hip_runtime.h>
#include <math.h>

typedef unsigned short u16;
typedef __attribute__((ext_vector_type(8))) short bffrag;   // 8 bf16 MFMA operand
typedef __attribute__((ext_vector_type(4))) float f32x4;    // MFMA accumulator
typedef __attribute__((ext_vector_type(4))) unsigned short us4;
typedef __attribute__((ext_vector_type(8))) unsigned short us8;

#define SCALE_QK (1.0f/32.0f)

// fp32 -> bf16 round-to-nearest-even (bit trick, NaN-free inputs)
__device__ __forceinline__ u16 f2bf(float f) {
    unsigned u = __builtin_bit_cast(unsigned, f);
    u += 0x7fffu + ((u >> 16) & 1u);
    return (u16)(u >> 16);
}

__device__ __forceinline__ void gld16(const u16* g, u16* l) {
    __builtin_amdgcn_global_load_lds(
        (const __attribute__((address_space(1))) void*)g,
        (__attribute__((address_space(3))) void*)l, 16, 0, 0);
}

// ---------------- router (fp32, exact) ----------------
__global__ __launch_bounds__(256) void router_partial(const float* __restrict__ X,
                                                      const float* __restrict__ sW,
                                                      float* __restrict__ part) {
    float acc[32];
    #pragma unroll
    for (int a = 0; a < 32; ++a) acc[a] = 0.f;
    int tid = blockIdx.x * 256 + threadIdx.x;
    #pragma unroll
    for (int q = 0; q < 4; ++q) {
        int i = tid + q * 262144;
        float4 w0 = *(const float4*)(sW + (size_t)i * 8);
        float4 w1 = *(const float4*)(sW + (size_t)i * 8 + 4);
        #pragma unroll
        for (int b = 0; b < 4; ++b) {
            float x = X[((size_t)b << 20) + i];
            acc[b*8+0] += x * w0.x; acc[b*8+1] += x * w0.y;
            acc[b*8+2] += x * w0.z; acc[b*8+3] += x * w0.w;
            acc[b*8+4] += x * w1.x; acc[b*8+5] += x * w1.y;
            acc[b*8+6] += x * w1.z; acc[b*8+7] += x * w1.w;
        }
    }
    __shared__ float wsum[4][32];
    int lane = threadIdx.x & 63, wv = threadIdx.x >> 6;
    #pragma unroll
    for (int a = 0; a < 32; ++a) {
        float v = acc[a];
        #pragma unroll
        for (int off = 32; off; off >>= 1) v += __shfl_down(v, off, 64);
        if (lane == 0) wsum[wv][a] = v;
    }
    __syncthreads();
    int t = threadIdx.x;
    if (t < 32)
        part[(size_t)t * 1024 + blockIdx.x] = wsum[0][t] + wsum[1][t] + wsum[2][t] + wsum[3][t];
}

__global__ __launch_bounds__(256) void router_final(const float* __restrict__ part,
                                                    const float* __restrict__ sb,
                                                    int* __restrict__ sel_need) {
    __shared__ float ps[32][8];
    __shared__ float lg[32];
    int t = threadIdx.x, a = t >> 3, c = t & 7;
    {
        float s = 0.f;
        const float* p = part + (size_t)a * 1024 + c * 128;
        for (int i = 0; i < 128; ++i) s += p[i];
        ps[a][c] = s;
    }
    __syncthreads();
    if (t < 32) {
        float v = 0.f;
        #pragma unroll
        for (int j = 0; j < 8; ++j) v += ps[t][j];
        lg[t] = v + sb[t & 7];
    }
    __syncthreads();
    if (t < 4) {
        int base = t * 8;
        int e1 = 0; float v1 = lg[base];
        for (int e = 1; e < 8; ++e) { if (lg[base + e] > v1) { v1 = lg[base + e]; e1 = e; } }
        int e2 = -1; float v2 = -INFINITY;
        for (int e = 0; e < 8; ++e) {
            if (e == e1) continue;
            if (lg[base + e] > v2) { v2 = lg[base + e]; e2 = e; }
        }
        sel_need[t * 2] = e1; sel_need[t * 2 + 1] = e2;
    }
    __syncthreads();
    if (t < 8) {
        int need = 0;
        for (int j = 0; j < 8; ++j) need |= (sel_need[j] == t);
        sel_need[8 + t] = need;
    }
}

// cpart[e][hc][d] = sum_{h in chunk hc} bv[e][h] * Wff[e][h][d]  (h-chunked GEMV)
__global__ __launch_bounds__(256) void c1_partial(const float* __restrict__ Wff,
        const float* __restrict__ bv, const int* __restrict__ sel_need,
        float* __restrict__ cpart) {
    int e = blockIdx.z;
    if (!sel_need[8 + e]) return;
    int d = blockIdx.x * 256 + threadIdx.x;
    int h0 = blockIdx.y * 128;
    const float* W = Wff + ((size_t)e << 20) + (size_t)h0 * 1024 + d;
    const float* bvp = bv + e * 1024 + h0;
    float s = 0.f;
    #pragma unroll 4
    for (int h = 0; h < 128; ++h) s += bvp[h] * W[(size_t)h * 1024];
    cpart[(e * 8 + blockIdx.y) * 1024 + d] = s;
}

// ybias[b][d] = 2*(c1[e0]+c1[e1])[d] + bff[e0][d] + bff[e1][d]
__global__ __launch_bounds__(256) void ybias_kernel(const float* __restrict__ cpart,
        const float* __restrict__ bff, const int* __restrict__ sel,
        float* __restrict__ ybias) {
    int b = blockIdx.y;
    int d = blockIdx.x * 256 + threadIdx.x;
    int e0 = sel[b * 2], e1 = sel[b * 2 + 1];
    float c0 = 0.f, c1v = 0.f;
    #pragma unroll
    for (int hc = 0; hc < 8; ++hc) {
        c0  += cpart[(e0 * 8 + hc) * 1024 + d];
        c1v += cpart[(e1 * 8 + hc) * 1024 + d];
    }
    ybias[b * 1024 + d] = 2.f * (c0 + c1v) + bff[e0 * 1024 + d] + bff[e1 * 1024 + d];
}

// ---------------- converts ----------------
// y<4: X batch y -> Xb; y>=4: Wv expert y-4 (need-gated) -> WvB
__global__ __launch_bounds__(256) void cvt_misc(const float* __restrict__ X,
                                                const float* __restrict__ Wv,
                                                const int* __restrict__ sel_need,
                                                u16* __restrict__ Xb, u16* __restrict__ WvB) {
    int yz = blockIdx.y;
    const float* src; u16* dst;
    if (yz < 4) {
        src = X + ((size_t)yz << 20);  dst = Xb + ((size_t)yz << 20);
    } else {
        int e = yz - 4;
        if (!sel_need[8 + e]) return;
        src = Wv + ((size_t)e << 20);  dst = WvB + ((size_t)e << 20);
    }
    size_t i = (size_t)(blockIdx.x * 256 + threadIdx.x) * 8;
    float4 a = *(const float4*)(src + i);
    float4 b = *(const float4*)(src + i + 4);
    us8 o;
    o[0] = f2bf(a.x); o[1] = f2bf(a.y); o[2] = f2bf(a.z); o[3] = f2bf(a.w);
    o[4] = f2bf(b.x); o[5] = f2bf(b.y); o[6] = f2bf(b.z); o[7] = f2bf(b.w);
    *(us8*)(dst + i) = o;
}

// transpose + convert 1024x1024: z 0..23 = Wq/Wk/Wff expert matrices (need-gated),
// z 24..27 = X batch b (always)
__global__ __launch_bounds__(256) void cvt_wt(const float* __restrict__ Wq,
                                              const float* __restrict__ Wk,
                                              const float* __restrict__ Wff,
                                              const float* __restrict__ X,
                                              const int* __restrict__ sel_need,
                                              u16* __restrict__ WqT, u16* __restrict__ WkT,
                                              u16* __restrict__ WffT, u16* __restrict__ XbT) {
    int z = blockIdx.z;
    int type = z >> 3, e = z & 7;
    const float* src;
    u16* dst;
    if (type < 3) {
        if (!sel_need[8 + e]) return;
        src = (type == 0 ? Wq : type == 1 ? Wk : Wff) + ((size_t)e << 20);
        dst = (type == 0 ? WqT : type == 1 ? WkT : WffT) + ((size_t)e << 20);
    } else {
        int b = z & 3;
        src = X + ((size_t)b << 20);
        dst = XbT + ((size_t)b << 20);
    }
    __shared__ u16 lt[128 * 136];
    int R0 = blockIdx.y * 128, C0 = blockIdx.x * 128;
    int t = threadIdx.x;
    int c = t & 127;
    int rh = (t >> 7) * 4;
    #pragma unroll
    for (int it = 0; it < 16; ++it) {
        int r4 = it * 8 + rh;
        us4 o;
        #pragma unroll
        for (int j = 0; j < 4; ++j)
            o[j] = f2bf(src[(size_t)(R0 + r4 + j) * 1024 + C0 + c]);
        *(us4*)&lt[c * 136 + r4] = o;
    }
    __syncthreads();
    int dd = (t & 15) * 8;
    int hh = t >> 4;
    #pragma unroll
    for (int it = 0; it < 8; ++it) {
        int cr = it * 16 + hh;
        us8 o = *(const us8*)&lt[cr * 136 + dd];
        *(us8*)(dst + (size_t)(C0 + cr) * 1024 + R0 + dd) = o;
    }
}

// ============ 8-phase 256x256 MFMA core (T2+T3+T4+T5) ============
// C[m][n] = sum_k A[m][k]*B[n][k].  8 waves (2M x 4N), BK=64, 128 KB LDS dbuf.
__device__ __forceinline__ void stage_half8(const u16* g, int ld, u16* ldst, int tid) {
    int r = tid >> 3;
    int j = ((tid ^ r) & 7) * 8;
    gld16(g + (size_t)r * ld + j, ldst + tid * 8);
    gld16(g + (size_t)(r + 64) * ld + j, ldst + 4096 + tid * 8);
}

template<int Q, bool LASTVM>
__device__ __forceinline__ void phase8(const u16* Ac, const bffrag (&bfr)[4][2],
                                       f32x4 (&acc)[8][4], int rb, int l15, int x0,
                                       const u16* sg, int sld, u16* sdst, int tid) {
    bffrag af[2][2];
    #pragma unroll
    for (int mm = 0; mm < 2; ++mm) {
        int r = (rb + Q * 32 + mm * 16 + l15) * 64;
        af[mm][0] = *(const bffrag*)(Ac + r + x0);
        af[mm][1] = *(const bffrag*)(Ac + r + (x0 ^ 32));
    }
    __builtin_amdgcn_sched_barrier(0);
    stage_half8(sg, sld, sdst, tid);
    __builtin_amdgcn_sched_barrier(0);
    __builtin_amdgcn_s_barrier();
    asm volatile("s_waitcnt lgkmcnt(0)" ::: "memory");
    __builtin_amdgcn_sched_barrier(0);
    __builtin_amdgcn_s_setprio(1);
    #pragma unroll
    for (int ks = 0; ks < 2; ++ks)
        #pragma unroll
        for (int mm = 0; mm < 2; ++mm)
            #pragma unroll
            for (int nn = 0; nn < 4; ++nn)
                acc[Q*2+mm][nn] = __builtin_amdgcn_mfma_f32_16x16x32_bf16(
                    af[mm][ks], bfr[nn][ks], acc[Q*2+mm][nn], 0, 0, 0);
    __builtin_amdgcn_s_setprio(0);
    __builtin_amdgcn_sched_barrier(0);
    if (LASTVM) asm volatile("s_waitcnt vmcnt(4)" ::: "memory");
    __builtin_amdgcn_s_barrier();
}

__device__ __forceinline__ void gemm8(const u16* __restrict__ A, int lda,
                                      const u16* __restrict__ B, int ldb,
                                      int K, f32x4 (&acc)[8][4]) {
    __shared__ u16 lds[65536];                 // 128 KB: [buf][A 16384 | B 16384]
    const int tid = threadIdx.x, l = tid & 63, wid = tid >> 6;
    const int wr = wid >> 2, wc = wid & 3;
    const int l15 = l & 15;
    const int rb = wr * 128;                   // wave A-row base
    const int cb = wc * 64;                    // wave B-row base
    const int x0 = (((l >> 4) ^ (l & 7)) * 8); // swizzled k-slot, ks=0 (ks=1: ^32)
    const int m0 = blockIdx.y * 256, n0 = blockIdx.x * 256;
    const int nt = K >> 6;

    const u16* Ag = A + (size_t)m0 * lda;
    const u16* Bg = B + (size_t)n0 * ldb;

    // prologue: A(0) halves -> buf0, B(0) -> buf0, B(1) -> buf1
    stage_half8(Ag,                          lda, lds,                 tid);
    stage_half8(Ag + (size_t)128 * lda,      lda, lds + 8192,          tid);
    stage_half8(Bg,                          ldb, lds + 16384,         tid);
    stage_half8(Bg + (size_t)128 * ldb,      ldb, lds + 16384 + 8192,  tid);
    stage_half8(Bg + 64,                     ldb, lds + 32768 + 16384, tid);
    stage_half8(Bg + 64 + (size_t)128 * ldb, ldb, lds + 32768 + 16384 + 8192, tid);
    asm volatile("s_waitcnt vmcnt(4)" ::: "memory");
    __builtin_amdgcn_s_barrier();

    for (int t7 = 0; t7 < nt; ++t7) {
        const int cur = t7 & 1;
        u16* Ac = lds + cur * 32768;
        u16* Bc = Ac + 16384;
        u16* An = lds + (cur ^ 1) * 32768;
        const int ka = (t7 + 1 < nt ? t7 + 1 : nt - 1) << 6;   // A(kt+1) col off
        const int kb = (t7 + 2 < nt ? t7 + 2 : nt - 1) << 6;   // B(kt+2) col off
        const u16* sA0 = Ag + ka;
        const u16* sA1 = Ag + (size_t)128 * lda + ka;
        const u16* sB0 = Bg + kb;
        const u16* sB1 = Bg + (size_t)128 * ldb + kb;

        // B-frags for this K-tile (read in phase 0, used by all 4 phases)
        bffrag bfr[4][2];
        #pragma unroll
        for (int nn = 0; nn < 4; ++nn) {
            int r = (cb + nn * 16 + l15) * 64;
            bfr[nn][0] = *(const bffrag*)(Bc + r + x0);
            bfr[nn][1] = *(const bffrag*)(Bc + r + (x0 ^ 32));
        }
        phase8<0, false>(Ac, bfr, acc, rb, l15, x0, sA0, lda, An, tid);
        phase8<1, false>(Ac, bfr, acc, rb, l15, x0, sA1, lda, An + 8192, tid);
        phase8<2, false>(Ac, bfr, acc, rb, l15, x0, sB0, ldb, Bc, tid);
        phase8<3, true >(Ac, bfr, acc, rb, l15, x0, sB1, ldb, Bc + 8192, tid);
    }
}

__device__ __forceinline__ void zero8(f32x4 (&acc)[8][4]) {
    #pragma unroll
    for (int m = 0; m < 8; ++m)
        #pragma unroll
        for (int n = 0; n < 4; ++n)
            #pragma unroll
            for (int i = 0; i < 4; ++i) acc[m][n][i] = 0.f;
}

__device__ __forceinline__ void epi8_bf16(u16* __restrict__ C, int ldc,
                                          const f32x4 (&acc)[8][4],
                                          const float* __restrict__ biasN) {
    const int tid = threadIdx.x, l = tid & 63, wid = tid >> 6;
    const int wr = wid >> 2, wc = wid & 3;
    const int m0 = blockIdx.y * 256 + wr * 128, n0 = blockIdx.x * 256 + wc * 64;
    const int l15 = l & 15, l4 = (l >> 4) * 4;
    #pragma unroll
    for (int mt = 0; mt < 8; ++mt)
        #pragma unroll
        for (int nn = 0; nn < 4; ++nn) {
            int col = n0 + nn * 16 + l15;
            float bn = biasN ? biasN[col] : 0.f;
            #pragma unroll
            for (int i = 0; i < 4; ++i) {
                int row = m0 + mt * 16 + l4 + i;
                C[(size_t)row * ldc + col] = f2bf(acc[mt][nn][i] + bn);
            }
        }
}

__device__ __forceinline__ void epi8_f32(float* __restrict__ C, int ldc, float scale,
                                         const f32x4 (&acc)[8][4]) {
    const int tid = threadIdx.x, l = tid & 63, wid = tid >> 6;
    const int wr = wid >> 2, wc = wid & 3;
    const int m0 = blockIdx.y * 256 + wr * 128, n0 = blockIdx.x * 256 + wc * 64;
    const int l15 = l & 15, l4 = (l >> 4) * 4;
    #pragma unroll
    for (int mt = 0; mt < 8; ++mt)
        #pragma unroll
        for (int nn = 0; nn < 4; ++nn) {
            int col = n0 + nn * 16 + l15;
            #pragma unroll
            for (int i = 0; i < 4; ++i) {
                int row = m0 + mt * 16 + l4 + i;
                C[(size_t)row * ldc + col] = acc[mt][nn][i] * scale;
            }
        }
}

// D1: z 0..15, w=z>>3 (0=Q,1=K), bs=z&7
__global__ __launch_bounds__(512) void mfma8_qk(const u16* __restrict__ Xb,
        const u16* __restrict__ WqT, const u16* __restrict__ WkT,
        const float* __restrict__ bq, const float* __restrict__ bk,
        const int* __restrict__ sel, u16* __restrict__ Qb, u16* __restrict__ Kb) {
    int z = blockIdx.z, w = z >> 3, bs = z & 7;
    int b = bs >> 1, e = sel[bs];
    f32x4 acc[8][4]; zero8(acc);
    gemm8(Xb + ((size_t)b << 20), 1024, (w ? WkT : WqT) + ((size_t)e << 20), 1024, 1024, acc);
    epi8_bf16((w ? Kb : Qb) + ((size_t)bs << 20), 1024, acc, (w ? bk : bq) + e * 1024);
}

// D2: z<8 scores(bs=z); z 8..11 wvf half0 (b=z-8); z 12..15 wvf half1
__global__ __launch_bounds__(512) void mfma8_sw(const u16* __restrict__ Qb,
        const u16* __restrict__ Kb, const u16* __restrict__ WffT,
        const u16* __restrict__ WvB, const int* __restrict__ sel,
        float* __restrict__ S, float* __restrict__ P0, float* __restrict__ P1) {
    int z = blockIdx.z;
    f32x4 acc[8][4]; zero8(acc);
    if (z < 8) {
        gemm8(Qb + ((size_t)z << 20), 1024, Kb + ((size_t)z << 20), 1024, 1024, acc);
        epi8_f32(S + ((size_t)z << 20), 1024, SCALE_QK, acc);
    } else {
        int h = (z >= 12), b = z & 3, e = sel[b * 2 + h];
        gemm8(WffT + ((size_t)e << 20), 1024, WvB + ((size_t)e << 20), 1024, 1024, acc);
        epi8_f32((h ? P1 : P0) + ((size_t)b << 20), 1024, 1.0f, acc);
    }
}

// Wvfsum[b] = bf16(P0[b] + P1[b])
__global__ __launch_bounds__(256) void wvfadd(const float* __restrict__ P0,
                                              const float* __restrict__ P1,
                                              u16* __restrict__ W) {
    size_t i = (size_t)(blockIdx.x * 256 + threadIdx.x) * 8;
    float4 a0 = *(const float4*)(P0 + i),     a1 = *(const float4*)(P0 + i + 4);
    float4 b0 = *(const float4*)(P1 + i),     b1 = *(const float4*)(P1 + i + 4);
    us8 o;
    o[0] = f2bf(a0.x + b0.x); o[1] = f2bf(a0.y + b0.y);
    o[2] = f2bf(a0.z + b0.z); o[3] = f2bf(a0.w + b0.w);
    o[4] = f2bf(a1.x + b1.x); o[5] = f2bf(a1.y + b1.y);
    o[6] = f2bf(a1.z + b1.z); o[7] = f2bf(a1.w + b1.w);
    *(us8*)(W + i) = o;
}

// ---------------- 2-phase 128x128 core (small tail GEMMs) ----------------
__device__ __forceinline__ void stage_tile(const u16* a0, const u16* a1,
                                           const u16* b0, const u16* b1,
                                           u16* sa, u16* sb, int tid) {
    gld16(a0, &sa[tid * 8]);
    gld16(a1, &sa[2048 + tid * 8]);
    gld16(b0, &sb[tid * 8]);
    gld16(b1, &sb[2048 + tid * 8]);
}

__device__ __forceinline__ void gemm_ds(const u16* __restrict__ A, int lda,
                                        const u16* __restrict__ B, int ldb,
                                        int K, f32x4 (&acc)[4][4]) {
    __shared__ u16 sA[2][4096];
    __shared__ u16 sB[2][4096];
    const int tid = threadIdx.x, lane = tid & 63, wv = tid >> 6;
    const int wr = (wv >> 1) * 64, wc = (wv & 1) * 64;
    const int l15 = lane & 15, lk = (lane >> 4) * 8;
    const int m0 = blockIdx.y * 128, n0 = blockIdx.x * 128;
    const int r0 = tid >> 2, k8 = (tid & 3) * 8;

    const u16* a0 = A + (size_t)(m0 + r0) * lda + k8;
    const u16* a1 = A + (size_t)(m0 + 64 + r0) * lda + k8;
    const u16* b0 = B + (size_t)(n0 + r0) * ldb + k8;
    const u16* b1 = B + (size_t)(n0 + 64 + r0) * ldb + k8;

    stage_tile(a0, a1, b0, b1, sA[0], sB[0], tid);
    __syncthreads();

    const int nt = K >> 5;
    for (int t = 0; t < nt; ++t) {
        const int cur = t & 1;
        if (t + 1 < nt) {
            int k0 = (t + 1) << 5;
            stage_tile(a0 + k0, a1 + k0, b0 + k0, b1 + k0, sA[cur ^ 1], sB[cur ^ 1], tid);
        }
        bffrag av[4], bf[4];
        #pragma unroll
        for (int m = 0; m < 4; ++m)
            av[m] = *reinterpret_cast<const bffrag*>(&sA[cur][(wr + m * 16 + l15) * 32 + lk]);
        #pragma unroll
        for (int n = 0; n < 4; ++n)
            bf[n] = *reinterpret_cast<const bffrag*>(&sB[cur][(wc + n * 16 + l15) * 32 + lk]);
        #pragma unroll
        for (int m = 0; m < 4; ++m)
            #pragma unroll
            for (int n = 0; n < 4; ++n)
                acc[m][n] = __builtin_amdgcn_mfma_f32_16x16x32_bf16(av[m], bf[n], acc[m][n], 0, 0, 0);
        __syncthreads();
    }
}

__device__ __forceinline__ void zero_acc(f32x4 (&acc)[4][4]) {
    #pragma unroll
    for (int m = 0; m < 4; ++m)
        #pragma unroll
        for (int n = 0; n < 4; ++n)
            #pragma unroll
            for (int i = 0; i < 4; ++i) acc[m][n][i] = 0.f;
}

__device__ __forceinline__ void epilogue_bf16(u16* __restrict__ C, int ldc,
                                              const f32x4 (&acc)[4][4]) {
    const int tid = threadIdx.x, lane = tid & 63, wv = tid >> 6;
    const int wr = (wv >> 1) * 64, wc = (wv & 1) * 64;
    const int m0 = blockIdx.y * 128, n0 = blockIdx.x * 128;
    const int l15 = lane & 15, l4 = (lane >> 4) * 4;
    #pragma unroll
    for (int m = 0; m < 4; ++m)
        #pragma unroll
        for (int n = 0; n < 4; ++n) {
            int col = n0 + wc + n * 16 + l15;
            #pragma unroll
            for (int i = 0; i < 4; ++i) {
                int row = m0 + wr + m * 16 + l4 + i;
                C[(size_t)row * ldc + col] = f2bf(acc[m][n][i]);
            }
        }
}

__device__ __forceinline__ void epilogue_f32(float* __restrict__ C, int ldc,
                                             const f32x4 (&acc)[4][4],
                                             const float* __restrict__ bias1) {
    const int tid = threadIdx.x, lane = tid & 63, wv = tid >> 6;
    const int wr = (wv >> 1) * 64, wc = (wv & 1) * 64;
    const int m0 = blockIdx.y * 128, n0 = blockIdx.x * 128;
    const int l15 = lane & 15, l4 = (lane >> 4) * 4;
    #pragma unroll
    for (int m = 0; m < 4; ++m)
        #pragma unroll
        for (int n = 0; n < 4; ++n) {
            int col = n0 + wc + n * 16 + l15;
            float bn = bias1 ? bias1[col] : 0.f;
            #pragma unroll
            for (int i = 0; i < 4; ++i) {
                int row = m0 + wr + m * 16 + l4 + i;
                C[(size_t)row * ldc + col] = acc[m][n][i] + bn;
            }
        }
}

// A[b][s][t] = softmax(S[b,0]) + softmax(S[b,1])  -> bf16
__global__ __launch_bounds__(256) void sm_combine(const float* __restrict__ S, u16* __restrict__ Ab) {
    int bs = blockIdx.x, b = bs >> 10, s = bs & 1023;
    const float* S0 = S + ((size_t)(b * 2) << 20) + (size_t)s * 1024;
    const float* S1 = S0 + (1u << 20);
    int t = threadIdx.x, lane = t & 63, wv = t >> 6;
    float4 x0 = *(const float4*)(S0 + t * 4);
    float4 x1 = *(const float4*)(S1 + t * 4);
    float m0 = fmaxf(fmaxf(x0.x, x0.y), fmaxf(x0.z, x0.w));
    float m1 = fmaxf(fmaxf(x1.x, x1.y), fmaxf(x1.z, x1.w));
    #pragma unroll
    for (int off = 32; off; off >>= 1) {
        m0 = fmaxf(m0, __shfl_xor(m0, off, 64));
        m1 = fmaxf(m1, __shfl_xor(m1, off, 64));
    }
    __shared__ float wred[4][4];
    if (lane == 0) { wred[wv][0] = m0; wred[wv][1] = m1; }
    __syncthreads();
    m0 = fmaxf(fmaxf(wred[0][0], wred[1][0]), fmaxf(wred[2][0], wred[3][0]));
    m1 = fmaxf(fmaxf(wred[0][1], wred[1][1]), fmaxf(wred[2][1], wred[3][1]));
    float4 e0, e1;
    e0.x = __expf(x0.x - m0); e0.y = __expf(x0.y - m0); e0.z = __expf(x0.z - m0); e0.w = __expf(x0.w - m0);
    e1.x = __expf(x1.x - m1); e1.y = __expf(x1.y - m1); e1.z = __expf(x1.z - m1); e1.w = __expf(x1.w - m1);
    float s0 = e0.x + e0.y + e0.z + e0.w;
    float s1 = e1.x + e1.y + e1.z + e1.w;
    #pragma unroll
    for (int off = 32; off; off >>= 1) {
        s0 += __shfl_xor(s0, off, 64);
        s1 += __shfl_xor(s1, off, 64);
    }
    if (lane == 0) { wred[wv][2] = s0; wred[wv][3] = s1; }
    __syncthreads();
    s0 = wred[0][2] + wred[1][2] + wred[2][2] + wred[3][2];
    s1 = wred[0][3] + wred[1][3] + wred[2][3] + wred[3][3];
    float r0 = 1.f / s0, r1 = 1.f / s1;
    us4 o;
    o[0] = f2bf(e0.x * r0 + e1.x * r1); o[1] = f2bf(e0.y * r0 + e1.y * r1);
    o[2] = f2bf(e0.z * r0 + e1.z * r1); o[3] = f2bf(e0.w * r0 + e1.w * r1);
    *(us4*)(Ab + ((size_t)b << 20) + (size_t)s * 1024 + t * 4) = o;
}

// AX[b][s][d] = sum_t A[b][s][t] * X[b][t][d]   (B-operand = XbT[d][t])
__global__ __launch_bounds__(256) void mfma_ax(const u16* __restrict__ Abf,
        const u16* __restrict__ XbT, u16* __restrict__ AXbf) {
    int b = blockIdx.z;
    f32x4 acc[4][4]; zero_acc(acc);
    gemm_ds(Abf + ((size_t)b << 20), 1024, XbT + ((size_t)b << 20), 1024, 1024, acc);
    epilogue_bf16(AXbf + ((size_t)b << 20), 1024, acc);
}

// y[b][s][d2] = sum_d AX[b][s][d] * Wvfsum[b][d2][d] + ybias[b][d2]
__global__ __launch_bounds__(256) void mfma_y(const u16* __restrict__ AXbf,
        const u16* __restrict__ Wvfsum, const float* __restrict__ ybias,
        float* __restrict__ y) {
    int b = blockIdx.z;
    f32x4 acc[4][4]; zero_acc(acc);
    gemm_ds(AXbf + ((size_t)b << 20), 1024, Wvfsum + ((size_t)b << 20), 1024, 1024, acc);
    epilogue_f32(y + ((size_t)b << 20), 1024, acc, ybias + b * 1024);
}

// ---------------- launcher ----------------
extern "C" void kernel_launch(void* const* d_in, const int* in_sizes, int n_in,
                              void* d_out, int out_size, void* d_ws, size_t ws_size,
                              hipStream_t stream) {
    const float* X   = (const float*)d_in[0];
    const float* sW  = (const float*)d_in[2];
    const float* sb  = (const float*)d_in[3];
    const float* Wq  = (const float*)d_in[4];
    const float* bq  = (const float*)d_in[5];
    const float* Wk  = (const float*)d_in[6];
    const float* bk  = (const float*)d_in[7];
    const float* Wv  = (const float*)d_in[8];
    const float* bv  = (const float*)d_in[9];
    const float* Wff = (const float*)d_in[10];
    const float* bff = (const float*)d_in[11];
    float* y = (float*)d_out;

    char* w = (char*)d_ws;
    float* part  = (float*)w;                  // 128 KB (dead after router_final)
    float* cpart = (float*)w;                  // overlay: 256 KB (written after router_final)
    int*   sel   = (int*)(w + (1u << 18));     // at 256 KB
    float* ybias = (float*)(w + (1u << 18) + 256);  // 16 KB
    u16* base = (u16*)(w + (1u << 19));        // at 512 KB
    u16* Xb   = base;                          // 8 MB   [Wvfsum overlay]
    u16* XbT  = Xb   + (4u << 20);             // 8 MB
    u16* WqT  = XbT  + (4u << 20);             // 16 MB  [Abf overlay]
    u16* WkT  = WqT  + (8u << 20);             // 16 MB  [AXbf overlay]
    u16* WffT = WkT  + (8u << 20);             // 16 MB
    u16* WvB  = WffT + (8u << 20);             // 16 MB
    u16* Qb   = WvB  + (8u << 20);             // 16 MB
    u16* Kb   = Qb   + (8u << 20);             // 16 MB
    float* S  = (float*)(Kb + (8u << 20));     // 32 MB
    float* P0 = S  + (8u << 20);               // 16 MB
    float* P1 = P0 + (4u << 20);               // 16 MB
    u16* Wvfsum = Xb;    // Xb dead after mfma8_qk
    u16* Abf    = WqT;   // WqT dead after mfma8_qk
    u16* AXbf   = WkT;   // WkT dead after mfma8_qk

    router_partial<<<1024, 256, 0, stream>>>(X, sW, part);
    router_final<<<1, 256, 0, stream>>>(part, sb, sel);
    c1_partial<<<dim3(4, 8, 8), 256, 0, stream>>>(Wff, bv, sel, cpart);
    ybias_kernel<<<dim3(4, 4), 256, 0, stream>>>(cpart, bff, sel, ybias);
    cvt_misc<<<dim3(512, 12), 256, 0, stream>>>(X, Wv, sel, Xb, WvB);
    cvt_wt<<<dim3(8, 8, 28), 256, 0, stream>>>(Wq, Wk, Wff, X, sel, WqT, WkT, WffT, XbT);

    mfma8_qk<<<dim3(4, 4, 16), 512, 0, stream>>>(Xb, WqT, WkT, bq, bk, sel, Qb, Kb);
    mfma8_sw<<<dim3(4, 4, 16), 512, 0, stream>>>(Qb, Kb, WffT, WvB, sel, S, P0, P1);
    wvfadd<<<2048, 256, 0, stream>>>(P0, P1, Wvfsum);
    sm_combine<<<4096, 256, 0, stream>>>(S, Abf);
    mfma_ax<<<dim3(8, 8, 4), 256, 0, stream>>>(Abf, XbT, AXbf);
    mfma_y<<<dim3(8, 8, 4), 256, 0, stream>>>(AXbf, Wvfsum, ybias, y);
}

// Round 7
// 221.768 us; speedup vs baseline: 1.2403x; 1.0781x over previous
//
#include <hip/hip_runtime.h>
#include <math.h>

typedef unsigned short u16;
typedef __attribute__((ext_vector_type(8))) short bffrag;   // 8 bf16 MFMA operand
typedef __attribute__((ext_vector_type(4))) float f32x4;    // MFMA accumulator
typedef __attribute__((ext_vector_type(4))) unsigned short us4;
typedef __attribute__((ext_vector_type(8))) unsigned short us8;

#define SCALE_QK (1.0f/32.0f)

// fp32 -> bf16 round-to-nearest-even (bit trick, NaN-free inputs)
__device__ __forceinline__ u16 f2bf(float f) {
    unsigned u = __builtin_bit_cast(unsigned, f);
    u += 0x7fffu + ((u >> 16) & 1u);
    return (u16)(u >> 16);
}
__device__ __forceinline__ float bf2f(u16 v) {
    unsigned u = ((unsigned)v) << 16;
    return __builtin_bit_cast(float, u);
}

__device__ __forceinline__ void gld16(const u16* g, u16* l) {
    __builtin_amdgcn_global_load_lds(
        (const __attribute__((address_space(1))) void*)g,
        (__attribute__((address_space(3))) void*)l, 16, 0, 0);
}

// ---------------- router (fp32, exact) ----------------
__global__ __launch_bounds__(256) void router_partial(const float* __restrict__ X,
                                                      const float* __restrict__ sW,
                                                      float* __restrict__ part) {
    float acc[32];
    #pragma unroll
    for (int a = 0; a < 32; ++a) acc[a] = 0.f;
    int tid = blockIdx.x * 256 + threadIdx.x;
    #pragma unroll
    for (int q = 0; q < 4; ++q) {
        int i = tid + q * 262144;
        float4 w0 = *(const float4*)(sW + (size_t)i * 8);
        float4 w1 = *(const float4*)(sW + (size_t)i * 8 + 4);
        #pragma unroll
        for (int b = 0; b < 4; ++b) {
            float x = X[((size_t)b << 20) + i];
            acc[b*8+0] += x * w0.x; acc[b*8+1] += x * w0.y;
            acc[b*8+2] += x * w0.z; acc[b*8+3] += x * w0.w;
            acc[b*8+4] += x * w1.x; acc[b*8+5] += x * w1.y;
            acc[b*8+6] += x * w1.z; acc[b*8+7] += x * w1.w;
        }
    }
    __shared__ float wsum[4][32];
    int lane = threadIdx.x & 63, wv = threadIdx.x >> 6;
    #pragma unroll
    for (int a = 0; a < 32; ++a) {
        float v = acc[a];
        #pragma unroll
        for (int off = 32; off; off >>= 1) v += __shfl_down(v, off, 64);
        if (lane == 0) wsum[wv][a] = v;
    }
    __syncthreads();
    int t = threadIdx.x;
    if (t < 32)
        part[(size_t)t * 1024 + blockIdx.x] = wsum[0][t] + wsum[1][t] + wsum[2][t] + wsum[3][t];
}

__global__ __launch_bounds__(256) void router_final(const float* __restrict__ part,
                                                    const float* __restrict__ sb,
                                                    int* __restrict__ sel_need) {
    __shared__ float ps[32][8];
    __shared__ float lg[32];
    int t = threadIdx.x, a = t >> 3, c = t & 7;
    {
        float s = 0.f;
        const float* p = part + (size_t)a * 1024 + c * 128;
        for (int i = 0; i < 128; ++i) s += p[i];
        ps[a][c] = s;
    }
    __syncthreads();
    if (t < 32) {
        float v = 0.f;
        #pragma unroll
        for (int j = 0; j < 8; ++j) v += ps[t][j];
        lg[t] = v + sb[t & 7];
    }
    __syncthreads();
    if (t < 4) {
        int base = t * 8;
        int e1 = 0; float v1 = lg[base];
        for (int e = 1; e < 8; ++e) { if (lg[base + e] > v1) { v1 = lg[base + e]; e1 = e; } }
        int e2 = -1; float v2 = -INFINITY;
        for (int e = 0; e < 8; ++e) {
            if (e == e1) continue;
            if (lg[base + e] > v2) { v2 = lg[base + e]; e2 = e; }
        }
        sel_need[t * 2] = e1; sel_need[t * 2 + 1] = e2;
    }
    __syncthreads();
    if (t < 8) {
        int need = 0;
        for (int j = 0; j < 8; ++j) need |= (sel_need[j] == t);
        sel_need[8 + t] = need;
    }
}

// cpart[e][hc][d] = sum_{h in chunk hc} bv[e][h] * Wff[e][h][d]  (h-chunked GEMV)
__global__ __launch_bounds__(256) void c1_partial(const float* __restrict__ Wff,
        const float* __restrict__ bv, const int* __restrict__ sel_need,
        float* __restrict__ cpart) {
    int e = blockIdx.z;
    if (!sel_need[8 + e]) return;
    int d = blockIdx.x * 256 + threadIdx.x;
    int h0 = blockIdx.y * 128;
    const float* W = Wff + ((size_t)e << 20) + (size_t)h0 * 1024 + d;
    const float* bvp = bv + e * 1024 + h0;
    float s = 0.f;
    #pragma unroll 4
    for (int h = 0; h < 128; ++h) s += bvp[h] * W[(size_t)h * 1024];
    cpart[(e * 8 + blockIdx.y) * 1024 + d] = s;
}

// ybias[b][d] = 2*(c1[e0]+c1[e1])[d] + bff[e0][d] + bff[e1][d]
__global__ __launch_bounds__(256) void ybias_kernel(const float* __restrict__ cpart,
        const float* __restrict__ bff, const int* __restrict__ sel,
        float* __restrict__ ybias) {
    int b = blockIdx.y;
    int d = blockIdx.x * 256 + threadIdx.x;
    int e0 = sel[b * 2], e1 = sel[b * 2 + 1];
    float c0 = 0.f, c1v = 0.f;
    #pragma unroll
    for (int hc = 0; hc < 8; ++hc) {
        c0  += cpart[(e0 * 8 + hc) * 1024 + d];
        c1v += cpart[(e1 * 8 + hc) * 1024 + d];
    }
    ybias[b * 1024 + d] = 2.f * (c0 + c1v) + bff[e0 * 1024 + d] + bff[e1 * 1024 + d];
}

// ---------------- converts ----------------
// y<4: X batch y -> Xb; y>=4: Wv expert y-4 (need-gated) -> WvB
__global__ __launch_bounds__(256) void cvt_misc(const float* __restrict__ X,
                                                const float* __restrict__ Wv,
                                                const int* __restrict__ sel_need,
                                                u16* __restrict__ Xb, u16* __restrict__ WvB) {
    int yz = blockIdx.y;
    const float* src; u16* dst;
    if (yz < 4) {
        src = X + ((size_t)yz << 20);  dst = Xb + ((size_t)yz << 20);
    } else {
        int e = yz - 4;
        if (!sel_need[8 + e]) return;
        src = Wv + ((size_t)e << 20);  dst = WvB + ((size_t)e << 20);
    }
    size_t i = (size_t)(blockIdx.x * 256 + threadIdx.x) * 8;
    float4 a = *(const float4*)(src + i);
    float4 b = *(const float4*)(src + i + 4);
    us8 o;
    o[0] = f2bf(a.x); o[1] = f2bf(a.y); o[2] = f2bf(a.z); o[3] = f2bf(a.w);
    o[4] = f2bf(b.x); o[5] = f2bf(b.y); o[6] = f2bf(b.z); o[7] = f2bf(b.w);
    *(us8*)(dst + i) = o;
}

// transpose + convert 1024x1024: z 0..23 = Wq/Wk/Wff expert matrices (need-gated)
__global__ __launch_bounds__(256) void cvt_wt(const float* __restrict__ Wq,
                                              const float* __restrict__ Wk,
                                              const float* __restrict__ Wff,
                                              const int* __restrict__ sel_need,
                                              u16* __restrict__ WqT, u16* __restrict__ WkT,
                                              u16* __restrict__ WffT) {
    int z = blockIdx.z;
    int type = z >> 3, e = z & 7;
    if (!sel_need[8 + e]) return;
    const float* src = (type == 0 ? Wq : type == 1 ? Wk : Wff) + ((size_t)e << 20);
    u16* dst = (type == 0 ? WqT : type == 1 ? WkT : WffT) + ((size_t)e << 20);
    __shared__ u16 lt[128 * 136];
    int R0 = blockIdx.y * 128, C0 = blockIdx.x * 128;
    int t = threadIdx.x;
    int c = t & 127;
    int rh = (t >> 7) * 4;
    #pragma unroll
    for (int it = 0; it < 16; ++it) {
        int r4 = it * 8 + rh;
        us4 o;
        #pragma unroll
        for (int j = 0; j < 4; ++j)
            o[j] = f2bf(src[(size_t)(R0 + r4 + j) * 1024 + C0 + c]);
        *(us4*)&lt[c * 136 + r4] = o;
    }
    __syncthreads();
    int dd = (t & 15) * 8;
    int hh = t >> 4;
    #pragma unroll
    for (int it = 0; it < 8; ++it) {
        int cr = it * 16 + hh;
        us8 o = *(const us8*)&lt[cr * 136 + dd];
        *(us8*)(dst + (size_t)(C0 + cr) * 1024 + R0 + dd) = o;
    }
}

// ============ 8-phase 256x256 MFMA core (T2+T3+T4+T5) ============
__device__ __forceinline__ void stage_half8(const u16* g, int ld, u16* ldst, int tid) {
    int r = tid >> 3;
    int j = ((tid ^ r) & 7) * 8;
    gld16(g + (size_t)r * ld + j, ldst + tid * 8);
    gld16(g + (size_t)(r + 64) * ld + j, ldst + 4096 + tid * 8);
}

template<int Q, bool LASTVM>
__device__ __forceinline__ void phase8(const u16* Ac, const bffrag (&bfr)[4][2],
                                       f32x4 (&acc)[8][4], int rb, int l15, int x0,
                                       const u16* sg, int sld, u16* sdst, int tid) {
    bffrag af[2][2];
    #pragma unroll
    for (int mm = 0; mm < 2; ++mm) {
        int r = (rb + Q * 32 + mm * 16 + l15) * 64;
        af[mm][0] = *(const bffrag*)(Ac + r + x0);
        af[mm][1] = *(const bffrag*)(Ac + r + (x0 ^ 32));
    }
    __builtin_amdgcn_sched_barrier(0);
    stage_half8(sg, sld, sdst, tid);
    __builtin_amdgcn_sched_barrier(0);
    __builtin_amdgcn_s_barrier();
    asm volatile("s_waitcnt lgkmcnt(0)" ::: "memory");
    __builtin_amdgcn_sched_barrier(0);
    __builtin_amdgcn_s_setprio(1);
    #pragma unroll
    for (int ks = 0; ks < 2; ++ks)
        #pragma unroll
        for (int mm = 0; mm < 2; ++mm)
            #pragma unroll
            for (int nn = 0; nn < 4; ++nn)
                acc[Q*2+mm][nn] = __builtin_amdgcn_mfma_f32_16x16x32_bf16(
                    af[mm][ks], bfr[nn][ks], acc[Q*2+mm][nn], 0, 0, 0);
    __builtin_amdgcn_s_setprio(0);
    __builtin_amdgcn_sched_barrier(0);
    if (LASTVM) asm volatile("s_waitcnt vmcnt(4)" ::: "memory");
    __builtin_amdgcn_s_barrier();
}

__device__ __forceinline__ void gemm8(const u16* __restrict__ A, int lda,
                                      const u16* __restrict__ B, int ldb,
                                      int K, f32x4 (&acc)[8][4]) {
    __shared__ u16 lds[65536];                 // 128 KB: [buf][A 16384 | B 16384]
    const int tid = threadIdx.x, l = tid & 63, wid = tid >> 6;
    const int wr = wid >> 2, wc = wid & 3;
    const int l15 = l & 15;
    const int rb = wr * 128;                   // wave A-row base
    const int cb = wc * 64;                    // wave B-row base
    const int x0 = (((l >> 4) ^ (l & 7)) * 8); // swizzled k-slot, ks=0 (ks=1: ^32)
    const int m0 = blockIdx.y * 256, n0 = blockIdx.x * 256;
    const int nt = K >> 6;

    const u16* Ag = A + (size_t)m0 * lda;
    const u16* Bg = B + (size_t)n0 * ldb;

    // prologue: A(0) halves -> buf0, B(0) -> buf0, B(1) -> buf1
    stage_half8(Ag,                          lda, lds,                 tid);
    stage_half8(Ag + (size_t)128 * lda,      lda, lds + 8192,          tid);
    stage_half8(Bg,                          ldb, lds + 16384,         tid);
    stage_half8(Bg + (size_t)128 * ldb,      ldb, lds + 16384 + 8192,  tid);
    stage_half8(Bg + 64,                     ldb, lds + 32768 + 16384, tid);
    stage_half8(Bg + 64 + (size_t)128 * ldb, ldb, lds + 32768 + 16384 + 8192, tid);
    asm volatile("s_waitcnt vmcnt(4)" ::: "memory");
    __builtin_amdgcn_s_barrier();

    for (int t7 = 0; t7 < nt; ++t7) {
        const int cur = t7 & 1;
        u16* Ac = lds + cur * 32768;
        u16* Bc = Ac + 16384;
        u16* An = lds + (cur ^ 1) * 32768;
        const int ka = (t7 + 1 < nt ? t7 + 1 : nt - 1) << 6;   // A(kt+1) col off
        const int kb = (t7 + 2 < nt ? t7 + 2 : nt - 1) << 6;   // B(kt+2) col off
        const u16* sA0 = Ag + ka;
        const u16* sA1 = Ag + (size_t)128 * lda + ka;
        const u16* sB0 = Bg + kb;
        const u16* sB1 = Bg + (size_t)128 * ldb + kb;

        // B-frags for this K-tile (read in phase 0, used by all 4 phases)
        bffrag bfr[4][2];
        #pragma unroll
        for (int nn = 0; nn < 4; ++nn) {
            int r = (cb + nn * 16 + l15) * 64;
            bfr[nn][0] = *(const bffrag*)(Bc + r + x0);
            bfr[nn][1] = *(const bffrag*)(Bc + r + (x0 ^ 32));
        }
        phase8<0, false>(Ac, bfr, acc, rb, l15, x0, sA0, lda, An, tid);
        phase8<1, false>(Ac, bfr, acc, rb, l15, x0, sA1, lda, An + 8192, tid);
        phase8<2, false>(Ac, bfr, acc, rb, l15, x0, sB0, ldb, Bc, tid);
        phase8<3, true >(Ac, bfr, acc, rb, l15, x0, sB1, ldb, Bc + 8192, tid);
    }
}

__device__ __forceinline__ void zero8(f32x4 (&acc)[8][4]) {
    #pragma unroll
    for (int m = 0; m < 8; ++m)
        #pragma unroll
        for (int n = 0; n < 4; ++n)
            #pragma unroll
            for (int i = 0; i < 4; ++i) acc[m][n][i] = 0.f;
}

// bf16 epilogue with scale + optional col-bias
__device__ __forceinline__ void epi8_bf16(u16* __restrict__ C, int ldc, float scale,
                                          const f32x4 (&acc)[8][4],
                                          const float* __restrict__ biasN) {
    const int tid = threadIdx.x, l = tid & 63, wid = tid >> 6;
    const int wr = wid >> 2, wc = wid & 3;
    const int m0 = blockIdx.y * 256 + wr * 128, n0 = blockIdx.x * 256 + wc * 64;
    const int l15 = l & 15, l4 = (l >> 4) * 4;
    #pragma unroll
    for (int mt = 0; mt < 8; ++mt)
        #pragma unroll
        for (int nn = 0; nn < 4; ++nn) {
            int col = n0 + nn * 16 + l15;
            float bn = biasN ? biasN[col] : 0.f;
            #pragma unroll
            for (int i = 0; i < 4; ++i) {
                int row = m0 + mt * 16 + l4 + i;
                C[(size_t)row * ldc + col] = f2bf(acc[mt][nn][i] * scale + bn);
            }
        }
}

// D1: z 0..15, w=z>>3 (0=Q,1=K), bs=z&7
__global__ __launch_bounds__(512) void mfma8_qk(const u16* __restrict__ Xb,
        const u16* __restrict__ WqT, const u16* __restrict__ WkT,
        const float* __restrict__ bq, const float* __restrict__ bk,
        const int* __restrict__ sel, u16* __restrict__ Qb, u16* __restrict__ Kb) {
    int z = blockIdx.z, w = z >> 3, bs = z & 7;
    int b = bs >> 1, e = sel[bs];
    f32x4 acc[8][4]; zero8(acc);
    gemm8(Xb + ((size_t)b << 20), 1024, (w ? WkT : WqT) + ((size_t)e << 20), 1024, 1024, acc);
    epi8_bf16((w ? Kb : Qb) + ((size_t)bs << 20), 1024, 1.0f, acc, (w ? bk : bq) + e * 1024);
}

// D2: z<8 scores->Sb (bf16, scaled); z 8..15 wvf halves -> P0b/P1b (bf16)
__global__ __launch_bounds__(512) void mfma8_sw(const u16* __restrict__ Qb,
        const u16* __restrict__ Kb, const u16* __restrict__ WffT,
        const u16* __restrict__ WvB, const int* __restrict__ sel,
        u16* __restrict__ Sb, u16* __restrict__ P0b, u16* __restrict__ P1b) {
    int z = blockIdx.z;
    f32x4 acc[8][4]; zero8(acc);
    if (z < 8) {
        gemm8(Qb + ((size_t)z << 20), 1024, Kb + ((size_t)z << 20), 1024, 1024, acc);
        epi8_bf16(Sb + ((size_t)z << 20), 1024, SCALE_QK, acc, nullptr);
    } else {
        int h = (z >= 12), b = z & 3, e = sel[b * 2 + h];
        gemm8(WffT + ((size_t)e << 20), 1024, WvB + ((size_t)e << 20), 1024, 1024, acc);
        epi8_bf16((h ? P1b : P0b) + ((size_t)b << 20), 1024, 1.0f, acc, nullptr);
    }
}

// Wvfsum[b] = bf16(P0b[b] + P1b[b])   (bf16 in, fp32 add, bf16 out)
__global__ __launch_bounds__(256) void wvfadd(const u16* __restrict__ P0b,
                                              const u16* __restrict__ P1b,
                                              u16* __restrict__ W) {
    size_t i = (size_t)(blockIdx.x * 256 + threadIdx.x) * 8;
    us8 a = *(const us8*)(P0b + i);
    us8 b = *(const us8*)(P1b + i);
    us8 o;
    #pragma unroll
    for (int j = 0; j < 8; ++j) o[j] = f2bf(bf2f(a[j]) + bf2f(b[j]));
    *(us8*)(W + i) = o;
}

// ---------------- 2-phase 128x128 core (tail GEMMs, full 256-block fill) ----------------
__device__ __forceinline__ void stage_tile(const u16* a0, const u16* a1,
                                           const u16* b0, const u16* b1,
                                           u16* sa, u16* sb, int tid) {
    gld16(a0, &sa[tid * 8]);
    gld16(a1, &sa[2048 + tid * 8]);
    gld16(b0, &sb[tid * 8]);
    gld16(b1, &sb[2048 + tid * 8]);
}

__device__ __forceinline__ void gemm_ds(const u16* __restrict__ A, int lda,
                                        const u16* __restrict__ B, int ldb,
                                        int K, f32x4 (&acc)[4][4]) {
    __shared__ u16 sA[2][4096];
    __shared__ u16 sB[2][4096];
    const int tid = threadIdx.x, lane = tid & 63, wv = tid >> 6;
    const int wr = (wv >> 1) * 64, wc = (wv & 1) * 64;
    const int l15 = lane & 15, lk = (lane >> 4) * 8;
    const int m0 = blockIdx.y * 128, n0 = blockIdx.x * 128;
    const int r0 = tid >> 2, k8 = (tid & 3) * 8;

    const u16* a0 = A + (size_t)(m0 + r0) * lda + k8;
    const u16* a1 = A + (size_t)(m0 + 64 + r0) * lda + k8;
    const u16* b0 = B + (size_t)(n0 + r0) * ldb + k8;
    const u16* b1 = B + (size_t)(n0 + 64 + r0) * ldb + k8;

    stage_tile(a0, a1, b0, b1, sA[0], sB[0], tid);
    __syncthreads();

    const int nt = K >> 5;
    for (int t = 0; t < nt; ++t) {
        const int cur = t & 1;
        if (t + 1 < nt) {
            int k0 = (t + 1) << 5;
            stage_tile(a0 + k0, a1 + k0, b0 + k0, b1 + k0, sA[cur ^ 1], sB[cur ^ 1], tid);
        }
        bffrag av[4], bf[4];
        #pragma unroll
        for (int m = 0; m < 4; ++m)
            av[m] = *reinterpret_cast<const bffrag*>(&sA[cur][(wr + m * 16 + l15) * 32 + lk]);
        #pragma unroll
        for (int n = 0; n < 4; ++n)
            bf[n] = *reinterpret_cast<const bffrag*>(&sB[cur][(wc + n * 16 + l15) * 32 + lk]);
        #pragma unroll
        for (int m = 0; m < 4; ++m)
            #pragma unroll
            for (int n = 0; n < 4; ++n)
                acc[m][n] = __builtin_amdgcn_mfma_f32_16x16x32_bf16(av[m], bf[n], acc[m][n], 0, 0, 0);
        __syncthreads();
    }
}

__device__ __forceinline__ void zero_acc(f32x4 (&acc)[4][4]) {
    #pragma unroll
    for (int m = 0; m < 4; ++m)
        #pragma unroll
        for (int n = 0; n < 4; ++n)
            #pragma unroll
            for (int i = 0; i < 4; ++i) acc[m][n][i] = 0.f;
}

__device__ __forceinline__ void epilogue_bf16(u16* __restrict__ C, int ldc,
                                              const f32x4 (&acc)[4][4]) {
    const int tid = threadIdx.x, lane = tid & 63, wv = tid >> 6;
    const int wr = (wv >> 1) * 64, wc = (wv & 1) * 64;
    const int m0 = blockIdx.y * 128, n0 = blockIdx.x * 128;
    const int l15 = lane & 15, l4 = (lane >> 4) * 4;
    #pragma unroll
    for (int m = 0; m < 4; ++m)
        #pragma unroll
        for (int n = 0; n < 4; ++n) {
            int col = n0 + wc + n * 16 + l15;
            #pragma unroll
            for (int i = 0; i < 4; ++i) {
                int row = m0 + wr + m * 16 + l4 + i;
                C[(size_t)row * ldc + col] = f2bf(acc[m][n][i]);
            }
        }
}

__device__ __forceinline__ void epilogue_f32(float* __restrict__ C, int ldc,
                                             const f32x4 (&acc)[4][4],
                                             const float* __restrict__ bias1) {
    const int tid = threadIdx.x, lane = tid & 63, wv = tid >> 6;
    const int wr = (wv >> 1) * 64, wc = (wv & 1) * 64;
    const int m0 = blockIdx.y * 128, n0 = blockIdx.x * 128;
    const int l15 = lane & 15, l4 = (lane >> 4) * 4;
    #pragma unroll
    for (int m = 0; m < 4; ++m)
        #pragma unroll
        for (int n = 0; n < 4; ++n) {
            int col = n0 + wc + n * 16 + l15;
            float bn = bias1 ? bias1[col] : 0.f;
            #pragma unroll
            for (int i = 0; i < 4; ++i) {
                int row = m0 + wr + m * 16 + l4 + i;
                C[(size_t)row * ldc + col] = acc[m][n][i] + bn;
            }
        }
}

// A[b][s][t] = softmax(Sb[b,0]) + softmax(Sb[b,1])  (bf16 in -> bf16 out)
__global__ __launch_bounds__(256) void sm_combine(const u16* __restrict__ Sb, u16* __restrict__ Ab) {
    int bs = blockIdx.x, b = bs >> 10, s = bs & 1023;
    const u16* S0 = Sb + ((size_t)(b * 2) << 20) + (size_t)s * 1024;
    const u16* S1 = S0 + (1u << 20);
    int t = threadIdx.x, lane = t & 63, wv = t >> 6;
    us4 xv0 = *(const us4*)(S0 + t * 4);
    us4 xv1 = *(const us4*)(S1 + t * 4);
    float x0[4], x1[4];
    #pragma unroll
    for (int j = 0; j < 4; ++j) { x0[j] = bf2f(xv0[j]); x1[j] = bf2f(xv1[j]); }
    float m0 = fmaxf(fmaxf(x0[0], x0[1]), fmaxf(x0[2], x0[3]));
    float m1 = fmaxf(fmaxf(x1[0], x1[1]), fmaxf(x1[2], x1[3]));
    #pragma unroll
    for (int off = 32; off; off >>= 1) {
        m0 = fmaxf(m0, __shfl_xor(m0, off, 64));
        m1 = fmaxf(m1, __shfl_xor(m1, off, 64));
    }
    __shared__ float wred[4][4];
    if (lane == 0) { wred[wv][0] = m0; wred[wv][1] = m1; }
    __syncthreads();
    m0 = fmaxf(fmaxf(wred[0][0], wred[1][0]), fmaxf(wred[2][0], wred[3][0]));
    m1 = fmaxf(fmaxf(wred[0][1], wred[1][1]), fmaxf(wred[2][1], wred[3][1]));
    float e0[4], e1[4];
    #pragma unroll
    for (int j = 0; j < 4; ++j) { e0[j] = __expf(x0[j] - m0); e1[j] = __expf(x1[j] - m1); }
    float s0 = e0[0] + e0[1] + e0[2] + e0[3];
    float s1 = e1[0] + e1[1] + e1[2] + e1[3];
    #pragma unroll
    for (int off = 32; off; off >>= 1) {
        s0 += __shfl_xor(s0, off, 64);
        s1 += __shfl_xor(s1, off, 64);
    }
    if (lane == 0) { wred[wv][2] = s0; wred[wv][3] = s1; }
    __syncthreads();
    s0 = wred[0][2] + wred[1][2] + wred[2][2] + wred[3][2];
    s1 = wred[0][3] + wred[1][3] + wred[2][3] + wred[3][3];
    float r0 = 1.f / s0, r1 = 1.f / s1;
    us4 o;
    #pragma unroll
    for (int j = 0; j < 4; ++j) o[j] = f2bf(e0[j] * r0 + e1[j] * r1);
    *(us4*)(Ab + ((size_t)b << 20) + (size_t)s * 1024 + t * 4) = o;
}

// Mt[b][d2][t] = sum_d Wvfsum[b][d2][d] * X[b][t][d]
__global__ __launch_bounds__(256) void mfma_mt(const u16* __restrict__ Wvfsum,
        const u16* __restrict__ Xb, u16* __restrict__ Mtb) {
    int b = blockIdx.z;
    f32x4 acc[4][4]; zero_acc(acc);
    gemm_ds(Wvfsum + ((size_t)b << 20), 1024, Xb + ((size_t)b << 20), 1024, 1024, acc);
    epilogue_bf16(Mtb + ((size_t)b << 20), 1024, acc);
}

// y[b][s][d2] = sum_t A[b][s][t] * Mt[b][d2][t] + ybias[b][d2]
__global__ __launch_bounds__(256) void mfma_y(const u16* __restrict__ Abf,
        const u16* __restrict__ Mtb, const float* __restrict__ ybias,
        float* __restrict__ y) {
    int b = blockIdx.z;
    f32x4 acc[4][4]; zero_acc(acc);
    gemm_ds(Abf + ((size_t)b << 20), 1024, Mtb + ((size_t)b << 20), 1024, 1024, acc);
    epilogue_f32(y + ((size_t)b << 20), 1024, acc, ybias + b * 1024);
}

// ---------------- launcher ----------------
extern "C" void kernel_launch(void* const* d_in, const int* in_sizes, int n_in,
                              void* d_out, int out_size, void* d_ws, size_t ws_size,
                              hipStream_t stream) {
    const float* X   = (const float*)d_in[0];
    const float* sW  = (const float*)d_in[2];
    const float* sb  = (const float*)d_in[3];
    const float* Wq  = (const float*)d_in[4];
    const float* bq  = (const float*)d_in[5];
    const float* Wk  = (const float*)d_in[6];
    const float* bk  = (const float*)d_in[7];
    const float* Wv  = (const float*)d_in[8];
    const float* bv  = (const float*)d_in[9];
    const float* Wff = (const float*)d_in[10];
    const float* bff = (const float*)d_in[11];
    float* y = (float*)d_out;

    char* w = (char*)d_ws;
    float* part  = (float*)w;                  // 128 KB (dead after router_final)
    float* cpart = (float*)w;                  // overlay: 256 KB (written after router_final)
    int*   sel   = (int*)(w + (1u << 18));     // at 256 KB
    float* ybias = (float*)(w + (1u << 18) + 256);  // 16 KB
    u16* base = (u16*)(w + (1u << 19));        // at 512 KB
    u16* Xb   = base;                          // 8 MB
    u16* WqT  = Xb   + (4u << 20);             // 16 MB  [Abf overlay]
    u16* WkT  = WqT  + (8u << 20);             // 16 MB  [Mtb overlay]
    u16* WffT = WkT  + (8u << 20);             // 16 MB
    u16* WvB  = WffT + (8u << 20);             // 16 MB
    u16* Qb   = WvB  + (8u << 20);             // 16 MB  [Wvfsum overlay]
    u16* Kb   = Qb   + (8u << 20);             // 16 MB
    u16* Sb   = Kb   + (8u << 20);             // 16 MB (bf16 scores, 8 x 1M)
    u16* P0b  = Sb   + (8u << 20);             // 8 MB
    u16* P1b  = P0b  + (4u << 20);             // 8 MB
    u16* Abf    = WqT;   // WqT dead after mfma8_qk
    u16* Mtb    = WkT;   // WkT dead after mfma8_qk
    u16* Wvfsum = Qb;    // Qb dead after mfma8_sw

    router_partial<<<1024, 256, 0, stream>>>(X, sW, part);
    router_final<<<1, 256, 0, stream>>>(part, sb, sel);
    c1_partial<<<dim3(4, 8, 8), 256, 0, stream>>>(Wff, bv, sel, cpart);
    ybias_kernel<<<dim3(4, 4), 256, 0, stream>>>(cpart, bff, sel, ybias);
    cvt_misc<<<dim3(512, 12), 256, 0, stream>>>(X, Wv, sel, Xb, WvB);
    cvt_wt<<<dim3(8, 8, 24), 256, 0, stream>>>(Wq, Wk, Wff, sel, WqT, WkT, WffT);

    mfma8_qk<<<dim3(4, 4, 16), 512, 0, stream>>>(Xb, WqT, WkT, bq, bk, sel, Qb, Kb);
    mfma8_sw<<<dim3(4, 4, 16), 512, 0, stream>>>(Qb, Kb, WffT, WvB, sel, Sb, P0b, P1b);
    wvfadd<<<2048, 256, 0, stream>>>(P0b, P1b, Wvfsum);
    mfma_mt<<<dim3(8, 8, 4), 256, 0, stream>>>(Wvfsum, Xb, Mtb);
    sm_combine<<<4096, 256, 0, stream>>>(Sb, Abf);
    mfma_y<<<dim3(8, 8, 4), 256, 0, stream>>>(Abf, Mtb, ybias, y);
}